// Round 2
// baseline (4013.937 us; speedup 1.0000x reference)
//
#include <hip/hip_runtime.h>
#include <math.h>

#define NTOK 65536
#define C 180
#define RCHUNK 8192   // rows per attention/MLP chunk (= 32 windows)

__device__ __forceinline__ float gelu_f(float v) {
    return 0.5f * v * (1.f + erff(v * 0.7071067811865475f));
}

// window-row (shifted-window order) -> pixel row index in [0, 65536)
__device__ __forceinline__ int win2pix(int wrow) {
    int wi = wrow >> 8, ni = wrow & 255;
    int r2 = ((wi >> 4) << 4) | (ni >> 4);
    int c2 = ((wi & 15) << 4) | (ni & 15);
    int r = (r2 + 8) & 255, c = (c2 + 8) & 255;
    return (r << 8) | c;
}

// ---------------- LayerNorm ----------------
__global__ __launch_bounds__(256) void ln_k(const float* __restrict__ x,
                                            const float* __restrict__ g,
                                            const float* __restrict__ b,
                                            float* __restrict__ y) {
    const int wav = threadIdx.x >> 6;
    const int lane = threadIdx.x & 63;
    const int row = blockIdx.x * 4 + wav;
    const float* xr = x + (size_t)row * C;
    float v0 = xr[lane];
    float v1 = xr[lane + 64];
    float v2 = (lane < C - 128) ? xr[lane + 128] : 0.f;
    float sum = v0 + v1 + v2;
    float sq = v0 * v0 + v1 * v1 + v2 * v2;
#pragma unroll
    for (int off = 32; off >= 1; off >>= 1) {
        sum += __shfl_xor(sum, off, 64);
        sq += __shfl_xor(sq, off, 64);
    }
    const float mu = sum * (1.f / C);
    const float var = sq * (1.f / C) - mu * mu;
    const float rstd = rsqrtf(var + 1e-5f);
#pragma unroll
    for (int e = 0; e < 3; ++e) {
        int col = lane + 64 * e;
        if (col < C) {
            float vv = (col < 128) ? (e == 0 ? v0 : v1) : v2;
            y[(size_t)row * C + col] = (vv - mu) * rstd * g[col] + b[col];
        }
    }
}

// ---------------- weight transpose  OIHW -> [ch][tap][oc] ----------------
template <int CIN, int COUT>
__global__ void wtrans_k(const float* __restrict__ w, float* __restrict__ wT) {
    int idx = blockIdx.x * 256 + threadIdx.x;
    if (idx >= CIN * COUT * 9) return;
    int t9 = idx % 9;
    int rest = idx / 9;
    int ch = rest % CIN;
    int oc = rest / CIN;
    wT[(ch * 9 + t9) * COUT + oc] = w[idx];
}

// ---------------- rpb gather:  rpb_full[h][i][j] ----------------
__global__ void rpb_prep_k(const int* __restrict__ rpi, const float* __restrict__ table,
                           float* __restrict__ rpb) {
    int idx = blockIdx.x * 256 + threadIdx.x;  // 65536 = i*256+j
    int t = rpi[idx];
#pragma unroll
    for (int h = 0; h < 6; ++h) rpb[h * 65536 + idx] = table[t * 6 + h];
}

// ---------------- direct conv 3x3, NHWC, zero pad 1 ----------------
template <int CIN, int COUT, int CCH, int OCPB, int ACT>
__global__ __launch_bounds__(256) void conv_k(const float* __restrict__ in,
                                              const float* __restrict__ wT,
                                              const float* __restrict__ bias,
                                              float* __restrict__ out) {
    constexpr int CST = CCH + 1;
    __shared__ float sPatch[18 * 18 * CST];
    const int tid = threadIdx.x;
    const int tr0 = (blockIdx.x >> 4) * 16;
    const int tc0 = (blockIdx.x & 15) * 16;
    const int ocbase = blockIdx.y * OCPB;
    const int px = tid & 15, py = tid >> 4;
    const int r = tr0 + py, c = tc0 + px;

    float acc[OCPB];
#pragma unroll
    for (int i = 0; i < OCPB; ++i) acc[i] = bias[ocbase + i];

    for (int ch0 = 0; ch0 < CIN; ch0 += CCH) {
        for (int l = tid; l < 18 * 18 * CCH; l += 256) {
            int pp = l / CCH;
            int chl = l % CCH;
            int ppy = pp / 18, ppx = pp % 18;
            int rr = tr0 + ppy - 1, cc = tc0 + ppx - 1;
            float v = 0.f;
            if (rr >= 0 && rr < 256 && cc >= 0 && cc < 256)
                v = in[((size_t)(rr * 256 + cc)) * CIN + ch0 + chl];
            sPatch[pp * CST + chl] = v;
        }
        __syncthreads();
#pragma unroll
        for (int t9 = 0; t9 < 9; ++t9) {
            const int dy = t9 / 3, dx = t9 % 3;
            const int prow = ((py + dy) * 18 + (px + dx)) * CST;
            for (int chl = 0; chl < CCH; ++chl) {
                float xv = sPatch[prow + chl];
                const float4* wrow4 =
                    (const float4*)(wT + (size_t)((ch0 + chl) * 9 + t9) * COUT + ocbase);
#pragma unroll
                for (int i4 = 0; i4 < OCPB / 4; ++i4) {
                    float4 wv = wrow4[i4];
                    acc[4 * i4 + 0] += xv * wv.x;
                    acc[4 * i4 + 1] += xv * wv.y;
                    acc[4 * i4 + 2] += xv * wv.z;
                    acc[4 * i4 + 3] += xv * wv.w;
                }
            }
        }
        __syncthreads();
    }
    const size_t obase = (size_t)(r * 256 + c) * COUT + ocbase;
#pragma unroll
    for (int i = 0; i < OCPB; ++i) {
        float v = acc[i];
        if (ACT == 1) v = gelu_f(v);
        out[obase + i] = v;
    }
}

// ---------------- channel sums (stage 1) ----------------
__global__ __launch_bounds__(256) void chansum_k(const float* __restrict__ y2,
                                                 float* __restrict__ partials) {
    __shared__ float acc[C];
    const int tid = threadIdx.x;
    if (tid < C) acc[tid] = 0.f;
    __syncthreads();
    const size_t base = (size_t)blockIdx.x * 256 * C;
    for (int l = tid; l < 256 * C; l += 256) {
        atomicAdd(&acc[l % C], y2[base + l]);
    }
    __syncthreads();
    if (tid < C) partials[blockIdx.x * C + tid] = acc[tid];
}

// ---------------- channel attention MLP (stage 2, 1 block) ----------------
__global__ __launch_bounds__(256) void ca_k(const float* __restrict__ partials,
                                            const float* __restrict__ w1, const float* __restrict__ b1,
                                            const float* __restrict__ w2, const float* __restrict__ b2,
                                            float* __restrict__ scale) {
    __shared__ float mean[C];
    __shared__ float s1[6];
    const int tid = threadIdx.x;
    if (tid < C) {
        float s = 0.f;
        for (int b_ = 0; b_ < 256; ++b_) s += partials[b_ * C + tid];
        mean[tid] = s * (1.f / 65536.f);
    }
    __syncthreads();
    if (tid < 6) {
        float s = b1[tid];
        for (int ch = 0; ch < C; ++ch) s += mean[ch] * w1[tid * C + ch];
        s1[tid] = fmaxf(s, 0.f);
    }
    __syncthreads();
    if (tid < C) {
        float s = b2[tid];
#pragma unroll
        for (int j = 0; j < 6; ++j) s += s1[j] * w2[tid * 6 + j];
        scale[tid] = 1.f / (1.f + __expf(-s));
    }
}

// ---------------- tiled fp32 GEMM, 64x64 tile, 4x4/thread ----------------
// MODE 1: fc1  — C = gelu(A*B + bias)                (local rows)
// MODE 2: fc2  — C = A*B + bias + xres               (local rows)
// MODE 3: qkv  — A-rows permuted via win2pix(rowoff+row), C local
// MODE 4: proj — epilogue fused merge:
//   pix = win2pix(rowoff+row); Cm[pix]= xres[pix] + (A*B+bias) + Cm[pix]*scale[col]*0.01
template <int MODE>
__global__ __launch_bounds__(256) void gemm_k(const float* __restrict__ A,
                                              const float* __restrict__ B,
                                              const float* __restrict__ bias,
                                              const float* __restrict__ xres,
                                              const float* __restrict__ scale,
                                              float* __restrict__ Cmat,
                                              int M, int N, int K, int rowoff) {
    __shared__ float As[16][68];
    __shared__ float Bs[16][68];
    const int tid = threadIdx.x;
    const int m0 = blockIdx.y * 64, n0 = blockIdx.x * 64;
    const int tm = tid & 15, tn = tid >> 4;
    float acc[4][4] = {};
    const int am = tid >> 2;
    const int ak = (tid & 3) * 4;
    const int bk = tid >> 4;
    const int bn = (tid & 15) * 4;
    size_t arow;
    if (MODE == 3)
        arow = (size_t)win2pix(rowoff + m0 + am) * K;
    else
        arow = (size_t)(m0 + am) * K;
    for (int k0 = 0; k0 < K; k0 += 16) {
#pragma unroll
        for (int j = 0; j < 4; ++j) {
            int gk = k0 + ak + j;
            As[ak + j][am] = (gk < K) ? A[arow + gk] : 0.f;
        }
        const int gk = k0 + bk;
#pragma unroll
        for (int j = 0; j < 4; ++j) {
            int gn = n0 + bn + j;
            Bs[bk][bn + j] = (gk < K && gn < N) ? B[(size_t)gk * N + gn] : 0.f;
        }
        __syncthreads();
#pragma unroll
        for (int k = 0; k < 16; ++k) {
            float a[4], bb[4];
#pragma unroll
            for (int i = 0; i < 4; ++i) a[i] = As[k][tm * 4 + i];
#pragma unroll
            for (int j = 0; j < 4; ++j) bb[j] = Bs[k][tn * 4 + j];
#pragma unroll
            for (int i = 0; i < 4; ++i)
#pragma unroll
                for (int j = 0; j < 4; ++j) acc[i][j] += a[i] * bb[j];
        }
        __syncthreads();
    }
#pragma unroll
    for (int i = 0; i < 4; ++i) {
        int row = m0 + tm * 4 + i;
        size_t pixbase = 0;
        if (MODE == 4) pixbase = (size_t)win2pix(rowoff + row) * 180;
#pragma unroll
        for (int j = 0; j < 4; ++j) {
            int col = n0 + tn * 4 + j;
            if (col < N) {
                float v = acc[i][j] + bias[col];
                if (MODE == 1) v = gelu_f(v);
                if (MODE == 2) v += xres[(size_t)row * N + col];
                if (MODE == 4) {
                    size_t o = pixbase + col;
                    Cmat[o] = xres[o] + v + Cmat[o] * scale[col] * 0.01f;
                } else {
                    Cmat[(size_t)row * N + col] = v;
                }
            }
        }
    }
}

// ---------------- windowed attention, flash-style, one block per (window, head) ----------------
__global__ __launch_bounds__(256) void attn_k(const float* __restrict__ qkv,  // chunk-local
                                              const float* __restrict__ rpb,
                                              const float* __restrict__ mask,
                                              float* __restrict__ attn_out,   // chunk-local
                                              int wbase) {
    const int wl = blockIdx.x;          // local window 0..31
    const int wig = wbase + wl;         // global window 0..255
    const int h = blockIdx.y;           // 0..5
    const int tid = threadIdx.x;
    __shared__ float kk[256 * 30];
    __shared__ float vv[256 * 30];
    for (int l = tid; l < 256 * 30; l += 256) {
        int j = l / 30, d = l % 30;
        size_t row = (size_t)(wl * 256 + j) * 540;
        kk[l] = qkv[row + 180 + h * 30 + d];
        vv[l] = qkv[row + 360 + h * 30 + d];
    }
    __syncthreads();
    float q[30];
    const size_t lrow = (size_t)(wl * 256 + tid);
#pragma unroll
    for (int d = 0; d < 30; ++d) q[d] = qkv[lrow * 540 + h * 30 + d] * 0.18257418583505536f;
    const float* rrow = rpb + ((size_t)h * 256 + tid) * 256;
    const float* mrow = mask + ((size_t)(wig * 256 + tid)) * 256;
    float m = -1e30f, l = 0.f, o[30];
#pragma unroll
    for (int d = 0; d < 30; ++d) o[d] = 0.f;
    for (int c0 = 0; c0 < 256; c0 += 32) {
        float s[32];
#pragma unroll
        for (int j = 0; j < 32; ++j) {
            int jj = c0 + j;
            float dot = 0.f;
#pragma unroll
            for (int d = 0; d < 30; ++d) dot += q[d] * kk[jj * 30 + d];
            s[j] = dot + rrow[jj] + mrow[jj];
        }
        float mx = m;
#pragma unroll
        for (int j = 0; j < 32; ++j) mx = fmaxf(mx, s[j]);
        float sc = __expf(m - mx);
        l *= sc;
#pragma unroll
        for (int d = 0; d < 30; ++d) o[d] *= sc;
#pragma unroll
        for (int j = 0; j < 32; ++j) {
            float p = __expf(s[j] - mx);
            l += p;
            int jj = c0 + j;
#pragma unroll
            for (int d = 0; d < 30; ++d) o[d] += p * vv[jj * 30 + d];
        }
        m = mx;
    }
    const float inv = 1.f / l;
#pragma unroll
    for (int d = 0; d < 30; ++d) attn_out[lrow * 180 + h * 30 + d] = o[d] * inv;
}

extern "C" void kernel_launch(void* const* d_in, const int* in_sizes, int n_in, void* d_out,
                              int out_size, void* d_ws, size_t ws_size, hipStream_t stream) {
    (void)in_sizes; (void)n_in; (void)out_size; (void)ws_size;
    const float* x = (const float*)d_in[0];
    const int* rpi = (const int*)d_in[3];
    const float* mask = (const float*)d_in[4];
    const float* n1g = (const float*)d_in[5];
    const float* n1b = (const float*)d_in[6];
    const float* qkvw = (const float*)d_in[7];
    const float* qkvb = (const float*)d_in[8];
    const float* rpbt = (const float*)d_in[9];
    const float* projw = (const float*)d_in[10];
    const float* projb = (const float*)d_in[11];
    const float* c1w = (const float*)d_in[12];
    const float* c1b = (const float*)d_in[13];
    const float* c2w = (const float*)d_in[14];
    const float* c2b = (const float*)d_in[15];
    const float* ca1w = (const float*)d_in[16];
    const float* ca1b = (const float*)d_in[17];
    const float* ca2w = (const float*)d_in[18];
    const float* ca2b = (const float*)d_in[19];
    const float* n2g = (const float*)d_in[20];
    const float* n2b = (const float*)d_in[21];
    const float* f1w = (const float*)d_in[22];
    const float* f1b = (const float*)d_in[23];
    const float* f2w = (const float*)d_in[24];
    const float* f2b = (const float*)d_in[25];

    float* ws = (float*)d_ws;
    float* out = (float*)d_out;   // y2 -> x2 -> final output (in place, disjoint phases)

    const size_t SZ = (size_t)NTOK * C;        // 11,796,480
    // workspace layout (floats), total ~18.33M floats = 73.3 MB
    float* xn       = ws;                       // SZ: LN1 out; later LN2 out (xm)
    float* bufC     = xn + SZ;                  // RCHUNK*720 = 5,898,240: y1 / qkv+attn chunk / h1 chunk
    float* partials = bufC + (size_t)RCHUNK * 720;  // 46,080
    float* scale    = partials + 256 * C;       // 256 (padded)
    float* rpbf     = scale + 256;              // 6*65536 = 393,216
    float* wT1      = rpbf + 6 * 65536;         // 97,200
    float* wT2      = wT1 + 180 * 9 * 60;       // 97,200
    float* y1       = bufC;                     // NTOK*60 = 3,932,160 (fits in bufC)
    float* qkvC     = bufC;                     // RCHUNK*540
    float* attnC    = bufC + (size_t)RCHUNK * 540;  // RCHUNK*180
    float* h1       = bufC;                     // RCHUNK*720

    // prep
    rpb_prep_k<<<256, 256, 0, stream>>>(rpi, rpbt, rpbf);
    wtrans_k<180, 60><<<(180 * 60 * 9 + 255) / 256, 256, 0, stream>>>(c1w, wT1);
    wtrans_k<60, 180><<<(60 * 180 * 9 + 255) / 256, 256, 0, stream>>>(c2w, wT2);

    // LN1
    ln_k<<<NTOK / 4, 256, 0, stream>>>(x, n1g, n1b, xn);

    // CAB conv branch: y2 lives in d_out
    conv_k<180, 60, 36, 60, 1><<<dim3(256, 1), 256, 0, stream>>>(xn, wT1, c1b, y1);
    conv_k<60, 180, 30, 60, 0><<<dim3(256, 3), 256, 0, stream>>>(y1, wT2, c2b, out);
    chansum_k<<<256, 256, 0, stream>>>(out, partials);
    ca_k<<<1, 256, 0, stream>>>(partials, ca1w, ca1b, ca2w, ca2b, scale);

    // attention branch, 8 chunks of 32 windows; proj epilogue fuses the full merge
    for (int ck = 0; ck < 8; ++ck) {
        const int rowoff = ck * RCHUNK;
        gemm_k<3><<<dim3(9, RCHUNK / 64), 256, 0, stream>>>(xn, qkvw, qkvb, nullptr, nullptr,
                                                            qkvC, RCHUNK, 540, 180, rowoff);
        attn_k<<<dim3(32, 6), 256, 0, stream>>>(qkvC, rpbf, mask, attnC, ck * 32);
        gemm_k<4><<<dim3(3, RCHUNK / 64), 256, 0, stream>>>(attnC, projw, projb, x, scale,
                                                            out, RCHUNK, 180, 180, rowoff);
    }

    // LN2 (x2 is in d_out) -> xm in xn buffer
    ln_k<<<NTOK / 4, 256, 0, stream>>>(out, n2g, n2b, xn);

    // MLP, 8 chunks; fc2 adds residual x2 (d_out) and overwrites d_out in place
    for (int ck = 0; ck < 8; ++ck) {
        const float* xmc = xn + (size_t)ck * RCHUNK * C;
        float* oc = out + (size_t)ck * RCHUNK * C;
        gemm_k<1><<<dim3(12, RCHUNK / 64), 256, 0, stream>>>(xmc, f1w, f1b, nullptr, nullptr,
                                                             h1, RCHUNK, 720, 180, 0);
        gemm_k<2><<<dim3(3, RCHUNK / 64), 256, 0, stream>>>(h1, f2w, f2b, oc, nullptr,
                                                            oc, RCHUNK, 180, 720, 0);
    }
}

// Round 3
// 1743.099 us; speedup vs baseline: 2.3028x; 2.3028x over previous
//
#include <hip/hip_runtime.h>
#include <hip/hip_bf16.h>
#include <math.h>

#define NTOK 65536
#define C 180
#define KP1 192      // padded K for C=180
#define RCHUNK 16384 // rows per chunk (64 windows)

typedef __attribute__((ext_vector_type(8))) __bf16 bf16x8;
typedef __attribute__((ext_vector_type(4))) float floatx4;

__device__ __forceinline__ float gelu_f(float v) {
    return 0.5f * v * (1.f + erff(v * 0.7071067811865475f));
}
__device__ __forceinline__ float cvt(float v) { return v; }
__device__ __forceinline__ float cvt(__hip_bfloat16 v) { return __bfloat162float(v); }

// window-row (shifted-window order) -> pixel row index in [0, 65536)
__device__ __forceinline__ int win2pix(int wrow) {
    int wi = wrow >> 8, ni = wrow & 255;
    int r2 = ((wi >> 4) << 4) | (ni >> 4);
    int c2 = ((wi & 15) << 4) | (ni & 15);
    int r = (r2 + 8) & 255, c = (c2 + 8) & 255;
    return (r << 8) | c;
}

// ---------------- LayerNorm: fp32 in (stride 180) -> bf16 out (stride 192, zero pad) -----------
__global__ __launch_bounds__(256) void ln_k(const float* __restrict__ x,
                                            const float* __restrict__ g,
                                            const float* __restrict__ b,
                                            __hip_bfloat16* __restrict__ y) {
    const int wav = threadIdx.x >> 6;
    const int lane = threadIdx.x & 63;
    const int row = blockIdx.x * 4 + wav;
    const float* xr = x + (size_t)row * C;
    float v0 = xr[lane];
    float v1 = xr[lane + 64];
    float v2 = (lane < C - 128) ? xr[lane + 128] : 0.f;
    float sum = v0 + v1 + v2;
    float sq = v0 * v0 + v1 * v1 + v2 * v2;
#pragma unroll
    for (int off = 32; off >= 1; off >>= 1) {
        sum += __shfl_xor(sum, off, 64);
        sq += __shfl_xor(sq, off, 64);
    }
    const float mu = sum * (1.f / C);
    const float var = sq * (1.f / C) - mu * mu;
    const float rstd = rsqrtf(var + 1e-5f);
    __hip_bfloat16* yr = y + (size_t)row * KP1;
#pragma unroll
    for (int e = 0; e < 3; ++e) {
        int col = lane + 64 * e;
        float val = 0.f;
        if (col < C) {
            float vv = (e == 0) ? v0 : (e == 1 ? v1 : v2);
            val = (vv - mu) * rstd * g[col] + b[col];
        }
        yr[col] = __float2bfloat16(val);
    }
}

// ---------------- conv weight transpose  OIHW -> [ch*9+tap][oc] (fp32) ----------------
template <int CIN, int COUT>
__global__ void wtrans_k(const float* __restrict__ w, float* __restrict__ wT) {
    int idx = blockIdx.x * 256 + threadIdx.x;
    if (idx >= CIN * COUT * 9) return;
    int t9 = idx % 9;
    int rest = idx / 9;
    int ch = rest % CIN;
    int oc = rest / CIN;
    wT[(ch * 9 + t9) * COUT + oc] = w[idx];
}

// ---------------- GEMM weight prep: fp32 [K][N] -> bf16 B^T [NP][KPd] zero-padded --------------
__global__ void wprep_k(const float* __restrict__ w, __hip_bfloat16* __restrict__ bt,
                        int K, int N, int KPd, int NP) {
    int idx = blockIdx.x * 256 + threadIdx.x;
    if (idx >= NP * KPd) return;
    int n = idx / KPd, k = idx - n * KPd;
    float v = (n < N && k < K) ? w[(size_t)k * N + n] : 0.f;
    bt[idx] = __float2bfloat16(v);
}

// ---------------- rpb gather:  rpb_full[h][i][j] ----------------
__global__ void rpb_prep_k(const int* __restrict__ rpi, const float* __restrict__ table,
                           float* __restrict__ rpb) {
    int idx = blockIdx.x * 256 + threadIdx.x;
    int t = rpi[idx];
#pragma unroll
    for (int h = 0; h < 6; ++h) rpb[h * 65536 + idx] = table[t * 6 + h];
}

// ---------------- direct conv 3x3, NHWC, pad 1; 16x16 px tile x 16-oc group ----------------
template <typename T, int CIN, int ISTR, int COUT, int CCH, int ACT>
__global__ __launch_bounds__(256) void conv_k(const T* __restrict__ in,
                                              const float* __restrict__ wT,
                                              const float* __restrict__ bias,
                                              float* __restrict__ out) {
    constexpr int CST = CCH + 1;
    __shared__ float sP[18 * 18 * CST];
    __shared__ float sW[9 * CCH * 16];
    const int tid = threadIdx.x;
    const int tr0 = (blockIdx.x >> 4) * 16;
    const int tc0 = (blockIdx.x & 15) * 16;
    const int ocbase = blockIdx.y * 16;
    const int px = tid & 15, py = tid >> 4;
    float acc[16];
#pragma unroll
    for (int i = 0; i < 16; ++i) acc[i] = (ocbase + i < COUT) ? bias[ocbase + i] : 0.f;

    for (int ch0 = 0; ch0 < CIN; ch0 += CCH) {
        for (int l = tid; l < 324 * CCH; l += 256) {
            int pp = l / CCH, chl = l - pp * CCH;
            int ppy = pp / 18, ppx = pp - ppy * 18;
            int rr = tr0 + ppy - 1, cc = tc0 + ppx - 1;
            float v = 0.f;
            if (rr >= 0 && rr < 256 && cc >= 0 && cc < 256)
                v = cvt(in[(size_t)(rr * 256 + cc) * ISTR + ch0 + chl]);
            sP[pp * CST + chl] = v;
        }
        for (int l = tid; l < 9 * CCH * 16; l += 256) {
            int oc = l & 15;
            int rest = l >> 4;  // t9*CCH+chl
            int t9 = rest / CCH, chl = rest - t9 * CCH;
            float wv = (ocbase + oc < COUT)
                           ? wT[(size_t)((ch0 + chl) * 9 + t9) * COUT + ocbase + oc]
                           : 0.f;
            sW[rest * 16 + oc] = wv;
        }
        __syncthreads();
#pragma unroll
        for (int t9 = 0; t9 < 9; ++t9) {
            const int dy = t9 / 3, dx = t9 - 3 * (t9 / 3);
            const int prow = ((py + dy) * 18 + (px + dx)) * CST;
            const float* wb = &sW[t9 * CCH * 16];
            for (int chl = 0; chl < CCH; ++chl) {
                float xv = sP[prow + chl];
                const float4* w4 = (const float4*)(wb + chl * 16);
#pragma unroll
                for (int i4 = 0; i4 < 4; ++i4) {
                    float4 wv = w4[i4];
                    acc[4 * i4 + 0] += xv * wv.x;
                    acc[4 * i4 + 1] += xv * wv.y;
                    acc[4 * i4 + 2] += xv * wv.z;
                    acc[4 * i4 + 3] += xv * wv.w;
                }
            }
        }
        __syncthreads();
    }
    const size_t obase = (size_t)((tr0 + py) * 256 + tc0 + px) * COUT + ocbase;
#pragma unroll
    for (int i = 0; i < 16; ++i)
        if (ocbase + i < COUT) {
            float v = acc[i];
            if (ACT) v = gelu_f(v);
            out[obase + i] = v;
        }
}

// ---------------- channel sums: block = 256 pixels, 180 coalesced column threads --------------
__global__ __launch_bounds__(192) void chansum_k(const float* __restrict__ y2,
                                                 float* __restrict__ partials) {
    const int tid = threadIdx.x;
    if (tid >= C) return;
    const size_t base = (size_t)blockIdx.x * 256 * C;
    float s = 0.f;
    for (int p = 0; p < 256; ++p) s += y2[base + (size_t)p * C + tid];
    partials[blockIdx.x * C + tid] = s;
}

// ---------------- channel attention MLP (1 block) ----------------
__global__ __launch_bounds__(256) void ca_k(const float* __restrict__ partials,
                                            const float* __restrict__ w1, const float* __restrict__ b1,
                                            const float* __restrict__ w2, const float* __restrict__ b2,
                                            float* __restrict__ scale) {
    __shared__ float mean[C];
    __shared__ float s1[6];
    const int tid = threadIdx.x;
    if (tid < C) {
        float s = 0.f;
        for (int b_ = 0; b_ < 256; ++b_) s += partials[b_ * C + tid];
        mean[tid] = s * (1.f / 65536.f);
    }
    __syncthreads();
    if (tid < 6) {
        float s = b1[tid];
        for (int ch = 0; ch < C; ++ch) s += mean[ch] * w1[tid * C + ch];
        s1[tid] = fmaxf(s, 0.f);
    }
    __syncthreads();
    if (tid < C) {
        float s = b2[tid];
#pragma unroll
        for (int j = 0; j < 6; ++j) s += s1[j] * w2[tid * 6 + j];
        scale[tid] = 1.f / (1.f + __expf(-s));
    }
}

// ---------------- bf16 MFMA GEMM: BM=128 BN=64 BK=32, 4 waves (2x2), wave tile 64x32 ----------
// MODE 1 fc1: Cout bf16 = gelu(A*B+bias), pad cols -> 0
// MODE 2 fc2: Cout f32  = A*B+bias+xres (col<N only)
// MODE 3 qkv: A rows via win2pix(rowoff+m); Cout bf16 = A*B+bias, pad cols -> 0
// MODE 4 proj: Cout f32 at win2pix rows: xres[o] + (A*B+bias) + Cout[o]*scale[col]*0.01
template <int MODE>
__global__ __launch_bounds__(256) void mgemm_k(const unsigned short* __restrict__ A,
                                               const unsigned short* __restrict__ BT,
                                               const float* __restrict__ bias,
                                               const float* __restrict__ xres,
                                               const float* __restrict__ scale,
                                               void* __restrict__ Cout,
                                               int KPd, int N, int cstride, int rowoff) {
    __shared__ unsigned short As[128 * 40];
    __shared__ unsigned short Bs[64 * 40];
    const int tid = threadIdx.x;
    const int m0 = blockIdx.y * 128, n0 = blockIdx.x * 64;
    const int arow_l = tid >> 1;
    const int akofs = (tid & 1) * 16;
    size_t arow;
    if (MODE == 3)
        arow = (size_t)win2pix(rowoff + m0 + arow_l) * KPd;
    else
        arow = (size_t)(m0 + arow_l) * KPd;
    const int brow_l = tid >> 2;
    const int bkofs = (tid & 3) * 8;
    const size_t brow = (size_t)(n0 + brow_l) * KPd;
    const int wave = tid >> 6, lane = tid & 63;
    const int wm = (wave & 1) * 64, wn = (wave >> 1) * 32;
    const int fr = lane & 15, q = lane >> 4;
    floatx4 acc[4][2] = {};
    for (int k0 = 0; k0 < KPd; k0 += 32) {
        *(float4*)(&As[arow_l * 40 + akofs]) = *(const float4*)(A + arow + k0 + akofs);
        *(float4*)(&As[arow_l * 40 + akofs + 8]) = *(const float4*)(A + arow + k0 + akofs + 8);
        *(float4*)(&Bs[brow_l * 40 + bkofs]) = *(const float4*)(BT + brow + k0 + bkofs);
        __syncthreads();
        bf16x8 af[4], fB[2];
#pragma unroll
        for (int i = 0; i < 4; ++i)
            af[i] = *(const bf16x8*)(&As[(wm + i * 16 + fr) * 40 + q * 8]);
#pragma unroll
        for (int j = 0; j < 2; ++j)
            fB[j] = *(const bf16x8*)(&Bs[(wn + j * 16 + fr) * 40 + q * 8]);
#pragma unroll
        for (int i = 0; i < 4; ++i)
#pragma unroll
            for (int j = 0; j < 2; ++j)
                acc[i][j] = __builtin_amdgcn_mfma_f32_16x16x32_bf16(af[i], fB[j], acc[i][j], 0, 0, 0);
        __syncthreads();
    }
#pragma unroll
    for (int i = 0; i < 4; ++i) {
#pragma unroll
        for (int r = 0; r < 4; ++r) {
            const int grow = m0 + wm + i * 16 + q * 4 + r;
            int pix = 0;
            if (MODE == 4) pix = win2pix(rowoff + grow);
#pragma unroll
            for (int j = 0; j < 2; ++j) {
                const int col = n0 + wn + j * 16 + fr;
                float v = acc[i][j][r];
                if (MODE == 1) {
                    float vv = (col < N) ? gelu_f(v + bias[col]) : 0.f;
                    ((__hip_bfloat16*)Cout)[(size_t)grow * cstride + col] = __float2bfloat16(vv);
                } else if (MODE == 3) {
                    float vv = (col < N) ? (v + bias[col]) : 0.f;
                    ((__hip_bfloat16*)Cout)[(size_t)grow * cstride + col] = __float2bfloat16(vv);
                } else if (MODE == 2) {
                    if (col < N) {
                        float* o = (float*)Cout;
                        size_t ix = (size_t)grow * cstride + col;
                        o[ix] = v + bias[col] + xres[ix];
                    }
                } else if (MODE == 4) {
                    if (col < N) {
                        float* o = (float*)Cout;
                        size_t ix = (size_t)pix * 180 + col;
                        o[ix] = xres[ix] + v + bias[col] + o[ix] * scale[col] * 0.01f;
                    }
                }
            }
        }
    }
}

// ---------------- windowed attention, flash-style, block per (window, head) ----------------
__global__ __launch_bounds__(256) void attn_k(const __hip_bfloat16* __restrict__ qkv,  // stride 576
                                              const float* __restrict__ rpb,
                                              const float* __restrict__ mask,
                                              __hip_bfloat16* __restrict__ attn_out,   // stride 192
                                              int wbase) {
    const int wl = blockIdx.x;
    const int wig = wbase + wl;
    const int h = blockIdx.y;
    const int tid = threadIdx.x;
    __shared__ float kk[256 * 30];
    __shared__ float vv[256 * 30];
    for (int l = tid; l < 256 * 30; l += 256) {
        int j = l / 30, d = l - j * 30;
        size_t row = (size_t)(wl * 256 + j) * 576;
        kk[l] = __bfloat162float(qkv[row + 180 + h * 30 + d]);
        vv[l] = __bfloat162float(qkv[row + 360 + h * 30 + d]);
    }
    __syncthreads();
    float q[30];
    const size_t lrow = (size_t)(wl * 256 + tid);
#pragma unroll
    for (int d = 0; d < 30; ++d)
        q[d] = __bfloat162float(qkv[lrow * 576 + h * 30 + d]) * 0.18257418583505536f;
    const float* rrow = rpb + ((size_t)h * 256 + tid) * 256;
    const float* mrow = mask + ((size_t)(wig * 256 + tid)) * 256;
    float m = -1e30f, l = 0.f, o[30];
#pragma unroll
    for (int d = 0; d < 30; ++d) o[d] = 0.f;
    for (int c0 = 0; c0 < 256; c0 += 32) {
        float s[32];
#pragma unroll
        for (int j = 0; j < 32; ++j) {
            int jj = c0 + j;
            float dot = 0.f;
#pragma unroll
            for (int d = 0; d < 30; ++d) dot += q[d] * kk[jj * 30 + d];
            s[j] = dot + rrow[jj] + mrow[jj];
        }
        float mx = m;
#pragma unroll
        for (int j = 0; j < 32; ++j) mx = fmaxf(mx, s[j]);
        float sc = __expf(m - mx);
        l *= sc;
#pragma unroll
        for (int d = 0; d < 30; ++d) o[d] *= sc;
#pragma unroll
        for (int j = 0; j < 32; ++j) {
            float p = __expf(s[j] - mx);
            l += p;
            int jj = c0 + j;
#pragma unroll
            for (int d = 0; d < 30; ++d) o[d] += p * vv[jj * 30 + d];
        }
        m = mx;
    }
    const float inv = 1.f / l;
    __hip_bfloat16* orow = attn_out + lrow * KP1;
#pragma unroll
    for (int d = 0; d < 30; ++d) orow[h * 30 + d] = __float2bfloat16(o[d] * inv);
    if (h == 0) {
#pragma unroll
        for (int d = 180; d < 192; ++d) orow[d] = __float2bfloat16(0.f);
    }
}

extern "C" void kernel_launch(void* const* d_in, const int* in_sizes, int n_in, void* d_out,
                              int out_size, void* d_ws, size_t ws_size, hipStream_t stream) {
    (void)in_sizes; (void)n_in; (void)out_size; (void)ws_size;
    const float* x = (const float*)d_in[0];
    const int* rpi = (const int*)d_in[3];
    const float* mask = (const float*)d_in[4];
    const float* n1g = (const float*)d_in[5];
    const float* n1b = (const float*)d_in[6];
    const float* qkvw = (const float*)d_in[7];
    const float* qkvb = (const float*)d_in[8];
    const float* rpbt = (const float*)d_in[9];
    const float* projw = (const float*)d_in[10];
    const float* projb = (const float*)d_in[11];
    const float* c1w = (const float*)d_in[12];
    const float* c1b = (const float*)d_in[13];
    const float* c2w = (const float*)d_in[14];
    const float* c2b = (const float*)d_in[15];
    const float* ca1w = (const float*)d_in[16];
    const float* ca1b = (const float*)d_in[17];
    const float* ca2w = (const float*)d_in[18];
    const float* ca2b = (const float*)d_in[19];
    const float* n2g = (const float*)d_in[20];
    const float* n2b = (const float*)d_in[21];
    const float* f1w = (const float*)d_in[22];
    const float* f1b = (const float*)d_in[23];
    const float* f2w = (const float*)d_in[24];
    const float* f2b = (const float*)d_in[25];

    float* ws = (float*)d_ws;
    float* out = (float*)d_out;  // y2 -> x2 -> final output (in place, disjoint phases)

    // workspace layout (floats; every offset multiple of 4 -> 16B aligned). ~53.7 MB total.
    float* xn_f     = ws;                    // 6,291,456 (65536x192 bf16)
    float* bufC     = xn_f + 6291456;        // 6,291,456 (y1 f32 | qkvC+attnC bf16 | h1 bf16)
    float* partials = bufC + 6291456;        // 46,080
    float* scalep   = partials + 46080;      // 192
    float* rpbf     = scalep + 192;          // 393,216
    float* wT1      = rpbf + 393216;         // 97,200
    float* wT2      = wT1 + 97200;           // 97,200
    float* qkvbt_f  = wT2 + 97200;           // 55,296  (576x192 bf16)
    float* projbt_f = qkvbt_f + 55296;       // 18,432  (192x192 bf16)
    float* f1bt_f   = projbt_f + 18432;      // 73,728  (768x192 bf16)
    float* f2bt_f   = f1bt_f + 73728;        // 73,728  (192x768 bf16)

    __hip_bfloat16* xn    = (__hip_bfloat16*)xn_f;
    float*          y1    = bufC;
    __hip_bfloat16* qkvC  = (__hip_bfloat16*)bufC;                  // 16384x576
    __hip_bfloat16* attnC = (__hip_bfloat16*)(bufC + 4718592);      // 16384x192
    __hip_bfloat16* h1    = (__hip_bfloat16*)bufC;                  // 16384x768
    __hip_bfloat16* qkvbt  = (__hip_bfloat16*)qkvbt_f;
    __hip_bfloat16* projbt = (__hip_bfloat16*)projbt_f;
    __hip_bfloat16* f1bt   = (__hip_bfloat16*)f1bt_f;
    __hip_bfloat16* f2bt   = (__hip_bfloat16*)f2bt_f;

    // ---- prep ----
    rpb_prep_k<<<256, 256, 0, stream>>>(rpi, rpbt, rpbf);
    wtrans_k<180, 60><<<(180 * 60 * 9 + 255) / 256, 256, 0, stream>>>(c1w, wT1);
    wtrans_k<60, 180><<<(60 * 180 * 9 + 255) / 256, 256, 0, stream>>>(c2w, wT2);
    wprep_k<<<(576 * 192 + 255) / 256, 256, 0, stream>>>(qkvw, qkvbt, 180, 540, 192, 576);
    wprep_k<<<(192 * 192 + 255) / 256, 256, 0, stream>>>(projw, projbt, 180, 180, 192, 192);
    wprep_k<<<(768 * 192 + 255) / 256, 256, 0, stream>>>(f1w, f1bt, 180, 720, 192, 768);
    wprep_k<<<(192 * 768 + 255) / 256, 256, 0, stream>>>(f2w, f2bt, 720, 180, 768, 192);

    // ---- LN1 -> bf16 ----
    ln_k<<<NTOK / 4, 256, 0, stream>>>(x, n1g, n1b, xn);

    // ---- CAB conv branch: y2 lives in d_out ----
    conv_k<__hip_bfloat16, 180, 192, 60, 20, 1><<<dim3(256, 4), 256, 0, stream>>>(xn, wT1, c1b, y1);
    conv_k<float, 60, 60, 180, 20, 0><<<dim3(256, 12), 256, 0, stream>>>(y1, wT2, c2b, out);
    chansum_k<<<256, 192, 0, stream>>>(out, partials);
    ca_k<<<1, 256, 0, stream>>>(partials, ca1w, ca1b, ca2w, ca2b, scalep);

    // ---- attention branch, 4 chunks of 64 windows; proj epilogue fuses the merge ----
    for (int ck = 0; ck < 4; ++ck) {
        const int rowoff = ck * RCHUNK;
        mgemm_k<3><<<dim3(9, RCHUNK / 128), 256, 0, stream>>>(
            (const unsigned short*)xn, (const unsigned short*)qkvbt, qkvb, nullptr, nullptr,
            qkvC, 192, 540, 576, rowoff);
        attn_k<<<dim3(64, 6), 256, 0, stream>>>(qkvC, rpbf, mask, attnC, ck * 64);
        mgemm_k<4><<<dim3(3, RCHUNK / 128), 256, 0, stream>>>(
            (const unsigned short*)attnC, (const unsigned short*)projbt, projb, x, scalep,
            out, 192, 180, 180, rowoff);
    }

    // ---- LN2 (x2 in d_out) -> bf16 xm ----
    ln_k<<<NTOK / 4, 256, 0, stream>>>(out, n2g, n2b, xn);

    // ---- MLP, 4 chunks; fc2 adds residual and overwrites d_out in place ----
    for (int ck = 0; ck < 4; ++ck) {
        const int rowoff = ck * RCHUNK;
        mgemm_k<1><<<dim3(12, RCHUNK / 128), 256, 0, stream>>>(
            (const unsigned short*)(xn + (size_t)rowoff * KP1), (const unsigned short*)f1bt,
            f1b, nullptr, nullptr, h1, 192, 720, 768, 0);
        mgemm_k<2><<<dim3(3, RCHUNK / 128), 256, 0, stream>>>(
            (const unsigned short*)h1, (const unsigned short*)f2bt, f2b,
            out + (size_t)rowoff * 180, nullptr, out + (size_t)rowoff * 180, 768, 180, 180, 0);
    }
}

// Round 4
// 1078.951 us; speedup vs baseline: 3.7202x; 1.6156x over previous
//
#include <hip/hip_runtime.h>
#include <hip/hip_bf16.h>
#include <math.h>

#define NTOK 65536
#define C 180
#define KP1 192      // padded K for C=180
#define RCHUNK 16384 // rows per chunk (64 windows)

typedef __attribute__((ext_vector_type(8))) __bf16 bf16x8;
typedef __attribute__((ext_vector_type(4))) float floatx4;

__device__ __forceinline__ float gelu_f(float v) {
    return 0.5f * v * (1.f + erff(v * 0.7071067811865475f));
}

// window-row (shifted-window order) -> pixel row index in [0, 65536)
__device__ __forceinline__ int win2pix(int wrow) {
    int wi = wrow >> 8, ni = wrow & 255;
    int r2 = ((wi >> 4) << 4) | (ni >> 4);
    int c2 = ((wi & 15) << 4) | (ni & 15);
    int r = (r2 + 8) & 255, c = (c2 + 8) & 255;
    return (r << 8) | c;
}

// ---------------- LayerNorm: fp32 in (stride 180) -> bf16 out (stride 192, zero pad) -----------
__global__ __launch_bounds__(256) void ln_k(const float* __restrict__ x,
                                            const float* __restrict__ g,
                                            const float* __restrict__ b,
                                            __hip_bfloat16* __restrict__ y) {
    const int wav = threadIdx.x >> 6;
    const int lane = threadIdx.x & 63;
    const int row = blockIdx.x * 4 + wav;
    const float* xr = x + (size_t)row * C;
    float v0 = xr[lane];
    float v1 = xr[lane + 64];
    float v2 = (lane < C - 128) ? xr[lane + 128] : 0.f;
    float sum = v0 + v1 + v2;
    float sq = v0 * v0 + v1 * v1 + v2 * v2;
#pragma unroll
    for (int off = 32; off >= 1; off >>= 1) {
        sum += __shfl_xor(sum, off, 64);
        sq += __shfl_xor(sq, off, 64);
    }
    const float mu = sum * (1.f / C);
    const float var = sq * (1.f / C) - mu * mu;
    const float rstd = rsqrtf(var + 1e-5f);
    __hip_bfloat16* yr = y + (size_t)row * KP1;
#pragma unroll
    for (int e = 0; e < 3; ++e) {
        int col = lane + 64 * e;
        float val = 0.f;
        if (col < C) {
            float vv = (e == 0) ? v0 : (e == 1 ? v1 : v2);
            val = (vv - mu) * rstd * g[col] + b[col];
        }
        yr[col] = __float2bfloat16(val);
    }
}

// ---------------- conv weight pack: OIHW f32 -> bf16 [tap][oc(OCP)][ch(KP)] zero-padded --------
__global__ void wconv_k(const float* __restrict__ w, __hip_bfloat16* __restrict__ wb,
                        int O, int I, int OCP, int KP) {
    int idx = blockIdx.x * 256 + threadIdx.x;
    if (idx >= 9 * OCP * KP) return;
    int tap = idx / (OCP * KP);
    int rem = idx - tap * (OCP * KP);
    int oc = rem / KP, ch = rem - oc * KP;
    float v = (oc < O && ch < I) ? w[((size_t)(oc * I + ch)) * 9 + tap] : 0.f;
    wb[idx] = __float2bfloat16(v);
}

// ---------------- GEMM weight prep: fp32 [K][N] -> bf16 B^T [NP][KPd] zero-padded --------------
__global__ void wprep_k(const float* __restrict__ w, __hip_bfloat16* __restrict__ bt,
                        int K, int N, int KPd, int NP) {
    int idx = blockIdx.x * 256 + threadIdx.x;
    if (idx >= NP * KPd) return;
    int n = idx / KPd, k = idx - n * KPd;
    float v = (n < N && k < K) ? w[(size_t)k * N + n] : 0.f;
    bt[idx] = __float2bfloat16(v);
}

// ---------------- rpb gather:  rpb_full[h][i][j] ----------------
__global__ void rpb_prep_k(const int* __restrict__ rpi, const float* __restrict__ table,
                           float* __restrict__ rpb) {
    int idx = blockIdx.x * 256 + threadIdx.x;
    int t = rpi[idx];
#pragma unroll
    for (int h = 0; h < 6; ++h) rpb[h * 65536 + idx] = table[t * 6 + h];
}

// ---------------- MFMA implicit-GEMM conv 3x3, NHWC bf16 in, pad 1 ----------------
// Block: 256 px (16x16 tile) x 64 oc. K-loop: ch chunks of 32 x 9 taps.
template <int CINP, int COUT, int OSTR, int ACT, int OUTBF>
__global__ __launch_bounds__(256) void mconv_k(const __hip_bfloat16* __restrict__ in, int istr,
                                               const __hip_bfloat16* __restrict__ wb,
                                               const float* __restrict__ bias,
                                               void* __restrict__ outp) {
    __shared__ __hip_bfloat16 sP[324 * 40];
    __shared__ __hip_bfloat16 sW[9 * 64 * 40];
    const int tid = threadIdx.x;
    const int tr0 = (blockIdx.x >> 4) * 16, tc0 = (blockIdx.x & 15) * 16;
    const int ocbase = blockIdx.y * 64;
    const int w = tid >> 6, lane = tid & 63, fr = lane & 15, q = lane >> 4;
    constexpr int OCP = ((COUT + 63) / 64) * 64;
    floatx4 acc[4][4] = {};
    for (int c0 = 0; c0 < CINP; c0 += 32) {
        // stage 18x18 patch x 32 ch
        for (int l = tid; l < 324 * 4; l += 256) {
            int pos = l >> 2, part = l & 3;
            int pr = pos / 18, pc = pos - pr * 18;
            int gr = tr0 + pr - 1, gc = tc0 + pc - 1;
            float4 v = make_float4(0.f, 0.f, 0.f, 0.f);
            if (gr >= 0 && gr < 256 && gc >= 0 && gc < 256)
                v = *(const float4*)(in + (size_t)(gr * 256 + gc) * istr + c0 + part * 8);
            *(float4*)(sP + pos * 40 + part * 8) = v;
        }
        // stage weights: 9 taps x 64 oc x 32 ch
        for (int l = tid; l < 9 * 64 * 4; l += 256) {
            int part = l & 3, oc = (l >> 2) & 63, tap = l >> 8;
            *(float4*)(sW + tap * 2560 + oc * 40 + part * 8) =
                *(const float4*)(wb + (size_t)(tap * OCP + ocbase + oc) * CINP + c0 + part * 8);
        }
        __syncthreads();
#pragma unroll
        for (int tap = 0; tap < 9; ++tap) {
            const int dy = tap / 3, dx = tap - 3 * (tap / 3);
            bf16x8 af[4], bw[4];
#pragma unroll
            for (int mi = 0; mi < 4; ++mi) {
                int pr = 4 * w + mi + dy, pc = fr + dx;
                af[mi] = *(const bf16x8*)(sP + (pr * 18 + pc) * 40 + q * 8);
            }
#pragma unroll
            for (int nj = 0; nj < 4; ++nj)
                bw[nj] = *(const bf16x8*)(sW + tap * 2560 + (nj * 16 + fr) * 40 + q * 8);
#pragma unroll
            for (int mi = 0; mi < 4; ++mi)
#pragma unroll
                for (int nj = 0; nj < 4; ++nj)
                    acc[mi][nj] =
                        __builtin_amdgcn_mfma_f32_16x16x32_bf16(af[mi], bw[nj], acc[mi][nj], 0, 0, 0);
        }
        __syncthreads();
    }
#pragma unroll
    for (int mi = 0; mi < 4; ++mi) {
#pragma unroll
        for (int r = 0; r < 4; ++r) {
            const int irow = tr0 + 4 * w + mi;
            const int icol = tc0 + q * 4 + r;
            const size_t obase = (size_t)(irow * 256 + icol) * OSTR + ocbase;
#pragma unroll
            for (int nj = 0; nj < 4; ++nj) {
                int oc = ocbase + nj * 16 + fr;
                float bv = (oc < COUT) ? bias[oc] : 0.f;
                float v = acc[mi][nj][r] + bv;
                if (ACT) v = gelu_f(v);
                if (OUTBF) {
                    ((__hip_bfloat16*)outp)[obase + nj * 16 + fr] = __float2bfloat16(v);
                } else {
                    if (oc < COUT) ((float*)outp)[obase + nj * 16 + fr] = v;
                }
            }
        }
    }
}

// ---------------- channel sums ----------------
__global__ __launch_bounds__(192) void chansum_k(const float* __restrict__ y2,
                                                 float* __restrict__ partials) {
    const int tid = threadIdx.x;
    if (tid >= C) return;
    const size_t base = (size_t)blockIdx.x * 256 * C;
    float s = 0.f;
    for (int p = 0; p < 256; ++p) s += y2[base + (size_t)p * C + tid];
    partials[blockIdx.x * C + tid] = s;
}

// ---------------- channel attention MLP (1 block) ----------------
__global__ __launch_bounds__(256) void ca_k(const float* __restrict__ partials,
                                            const float* __restrict__ w1, const float* __restrict__ b1,
                                            const float* __restrict__ w2, const float* __restrict__ b2,
                                            float* __restrict__ scale) {
    __shared__ float mean[C];
    __shared__ float s1[6];
    const int tid = threadIdx.x;
    if (tid < C) {
        float s = 0.f;
        for (int b_ = 0; b_ < 256; ++b_) s += partials[b_ * C + tid];
        mean[tid] = s * (1.f / 65536.f);
    }
    __syncthreads();
    if (tid < 6) {
        float s = b1[tid];
        for (int ch = 0; ch < C; ++ch) s += mean[ch] * w1[tid * C + ch];
        s1[tid] = fmaxf(s, 0.f);
    }
    __syncthreads();
    if (tid < C) {
        float s = b2[tid];
#pragma unroll
        for (int j = 0; j < 6; ++j) s += s1[j] * w2[tid * 6 + j];
        scale[tid] = 1.f / (1.f + __expf(-s));
    }
}

// ---------------- bf16 MFMA GEMM: BM=128 BN=64 BK=32, 4 waves (2x2), wave tile 64x32 ----------
template <int MODE>
__global__ __launch_bounds__(256) void mgemm_k(const unsigned short* __restrict__ A,
                                               const unsigned short* __restrict__ BT,
                                               const float* __restrict__ bias,
                                               const float* __restrict__ xres,
                                               const float* __restrict__ scale,
                                               void* __restrict__ Cout,
                                               int KPd, int N, int cstride, int rowoff) {
    __shared__ unsigned short As[128 * 40];
    __shared__ unsigned short Bs[64 * 40];
    const int tid = threadIdx.x;
    const int m0 = blockIdx.y * 128, n0 = blockIdx.x * 64;
    const int arow_l = tid >> 1;
    const int akofs = (tid & 1) * 16;
    size_t arow;
    if (MODE == 3)
        arow = (size_t)win2pix(rowoff + m0 + arow_l) * KPd;
    else
        arow = (size_t)(m0 + arow_l) * KPd;
    const int brow_l = tid >> 2;
    const int bkofs = (tid & 3) * 8;
    const size_t brow = (size_t)(n0 + brow_l) * KPd;
    const int wave = tid >> 6, lane = tid & 63;
    const int wm = (wave & 1) * 64, wn = (wave >> 1) * 32;
    const int fr = lane & 15, q = lane >> 4;
    floatx4 acc[4][2] = {};
    for (int k0 = 0; k0 < KPd; k0 += 32) {
        *(float4*)(&As[arow_l * 40 + akofs]) = *(const float4*)(A + arow + k0 + akofs);
        *(float4*)(&As[arow_l * 40 + akofs + 8]) = *(const float4*)(A + arow + k0 + akofs + 8);
        *(float4*)(&Bs[brow_l * 40 + bkofs]) = *(const float4*)(BT + brow + k0 + bkofs);
        __syncthreads();
        bf16x8 af[4], fB[2];
#pragma unroll
        for (int i = 0; i < 4; ++i)
            af[i] = *(const bf16x8*)(&As[(wm + i * 16 + fr) * 40 + q * 8]);
#pragma unroll
        for (int j = 0; j < 2; ++j)
            fB[j] = *(const bf16x8*)(&Bs[(wn + j * 16 + fr) * 40 + q * 8]);
#pragma unroll
        for (int i = 0; i < 4; ++i)
#pragma unroll
            for (int j = 0; j < 2; ++j)
                acc[i][j] = __builtin_amdgcn_mfma_f32_16x16x32_bf16(af[i], fB[j], acc[i][j], 0, 0, 0);
        __syncthreads();
    }
#pragma unroll
    for (int i = 0; i < 4; ++i) {
#pragma unroll
        for (int r = 0; r < 4; ++r) {
            const int grow = m0 + wm + i * 16 + q * 4 + r;
            int pix = 0;
            if (MODE == 4) pix = win2pix(rowoff + grow);
#pragma unroll
            for (int j = 0; j < 2; ++j) {
                const int col = n0 + wn + j * 16 + fr;
                float v = acc[i][j][r];
                if (MODE == 1) {
                    float vv = (col < N) ? gelu_f(v + bias[col]) : 0.f;
                    ((__hip_bfloat16*)Cout)[(size_t)grow * cstride + col] = __float2bfloat16(vv);
                } else if (MODE == 3) {
                    float vv = (col < N) ? (v + bias[col]) : 0.f;
                    ((__hip_bfloat16*)Cout)[(size_t)grow * cstride + col] = __float2bfloat16(vv);
                } else if (MODE == 2) {
                    if (col < N) {
                        float* o = (float*)Cout;
                        size_t ix = (size_t)grow * cstride + col;
                        o[ix] = v + bias[col] + xres[ix];
                    }
                } else if (MODE == 4) {
                    if (col < N) {
                        float* o = (float*)Cout;
                        size_t ix = (size_t)pix * 180 + col;
                        o[ix] = xres[ix] + v + bias[col] + o[ix] * scale[col] * 0.01f;
                    }
                }
            }
        }
    }
}

// ---------------- MFMA flash attention: block per (window, head), 4 waves x 64 q-rows ---------
__global__ __launch_bounds__(256) void attn2_k(const __hip_bfloat16* __restrict__ qkv,  // [16384][576]
                                               const float* __restrict__ rpb,
                                               const float* __restrict__ mask,
                                               __hip_bfloat16* __restrict__ attn_out,   // [16384][192]
                                               int wbase) {
    const int wl = blockIdx.x, h = blockIdx.y;
    const int wig = wbase + wl;
    const int tid = threadIdx.x;
    const int w = tid >> 6, lane = tid & 63;
    const int fr = lane & 15, q = lane >> 4;
    __shared__ __hip_bfloat16 kk[256 * 40];   // [key][d pad40], pre-scaled
    __shared__ __hip_bfloat16 vT[32 * 264];   // [d][key pad264]
    __shared__ __hip_bfloat16 pbuf[4 * 64 * 72];  // per-wave P buffer [64 m][72 pad]

    {   // staging: thread = key
        const int key = tid;
        const __hip_bfloat16* src = qkv + (size_t)(wl * 256 + key) * 576 + 180 + h * 30;
#pragma unroll
        for (int d = 0; d < 30; ++d) {
            kk[key * 40 + d] =
                __float2bfloat16(__bfloat162float(src[d]) * 0.18257418583505536f);
            vT[d * 264 + key] = src[180 + d];
        }
#pragma unroll
        for (int d = 30; d < 40; ++d) kk[key * 40 + d] = __float2bfloat16(0.f);
    }
    for (int l = tid; l < 2 * 264; l += 256) vT[30 * 264 + l] = __float2bfloat16(0.f);
    __syncthreads();

    // Q fragments (direct from global; d 30,31 garbage annihilated by kk zeros)
    const int rowbase = wl * 256 + w * 64;
    union U8 { unsigned int u[4]; bf16x8 v; };
    bf16x8 qf[4];
#pragma unroll
    for (int mi = 0; mi < 4; ++mi) {
        const unsigned int* p32 =
            (const unsigned int*)(qkv + (size_t)(rowbase + mi * 16 + fr) * 576 + h * 30);
        U8 t;
#pragma unroll
        for (int jj = 0; jj < 4; ++jj) t.u[jj] = p32[q * 4 + jj];
        qf[mi] = t.v;
    }

    float m_[4][4], l_[4][4];
#pragma unroll
    for (int mi = 0; mi < 4; ++mi)
#pragma unroll
        for (int r = 0; r < 4; ++r) { m_[mi][r] = -1e30f; l_[mi][r] = 0.f; }
    floatx4 o_[4][2] = {};
    __hip_bfloat16* pb = pbuf + w * 4608;

    for (int nc = 0; nc < 4; ++nc) {
        bf16x8 kf[4];
#pragma unroll
        for (int nj = 0; nj < 4; ++nj)
            kf[nj] = *(const bf16x8*)(kk + (nc * 64 + nj * 16 + fr) * 40 + q * 8);
        floatx4 s_[4][4] = {};
#pragma unroll
        for (int mi = 0; mi < 4; ++mi)
#pragma unroll
            for (int nj = 0; nj < 4; ++nj)
                s_[mi][nj] = __builtin_amdgcn_mfma_f32_16x16x32_bf16(qf[mi], kf[nj], s_[mi][nj], 0, 0, 0);
        // add rpb + mask (C-layout: row = q*4+r, col = fr)
#pragma unroll
        for (int mi = 0; mi < 4; ++mi) {
#pragma unroll
            for (int r = 0; r < 4; ++r) {
                const int row = w * 64 + mi * 16 + q * 4 + r;
                const float* mr = mask + ((size_t)wig * 256 + row) * 256 + nc * 64;
                const float* rr = rpb + ((size_t)h * 256 + row) * 256 + nc * 64;
#pragma unroll
                for (int nj = 0; nj < 4; ++nj) {
                    int cl = nj * 16 + fr;
                    s_[mi][nj][r] += mr[cl] + rr[cl];
                }
            }
        }
        // online softmax per row (reduce over 16 fr lanes)
#pragma unroll
        for (int mi = 0; mi < 4; ++mi) {
#pragma unroll
            for (int r = 0; r < 4; ++r) {
                float mx = s_[mi][0][r];
#pragma unroll
                for (int nj = 1; nj < 4; ++nj) mx = fmaxf(mx, s_[mi][nj][r]);
#pragma unroll
                for (int off = 1; off <= 8; off <<= 1) mx = fmaxf(mx, __shfl_xor(mx, off, 64));
                float mnew = fmaxf(m_[mi][r], mx);
                float alpha = __expf(m_[mi][r] - mnew);
                float rs = 0.f;
#pragma unroll
                for (int nj = 0; nj < 4; ++nj) {
                    float p = __expf(s_[mi][nj][r] - mnew);
                    s_[mi][nj][r] = p;
                    rs += p;
                }
#pragma unroll
                for (int off = 1; off <= 8; off <<= 1) rs += __shfl_xor(rs, off, 64);
                l_[mi][r] = l_[mi][r] * alpha + rs;
                m_[mi][r] = mnew;
                o_[mi][0][r] *= alpha;
                o_[mi][1][r] *= alpha;
            }
        }
        // P -> per-wave LDS (C-layout scatter), then PV via MFMA (A-layout reads)
#pragma unroll
        for (int mi = 0; mi < 4; ++mi)
#pragma unroll
            for (int nj = 0; nj < 4; ++nj)
#pragma unroll
                for (int r = 0; r < 4; ++r)
                    pb[(mi * 16 + q * 4 + r) * 72 + nj * 16 + fr] = __float2bfloat16(s_[mi][nj][r]);
#pragma unroll
        for (int ki = 0; ki < 2; ++ki) {
            bf16x8 pa[4], vb[2];
#pragma unroll
            for (int mi = 0; mi < 4; ++mi)
                pa[mi] = *(const bf16x8*)(pb + (mi * 16 + fr) * 72 + ki * 32 + q * 8);
#pragma unroll
            for (int dj = 0; dj < 2; ++dj)
                vb[dj] = *(const bf16x8*)(vT + (dj * 16 + fr) * 264 + nc * 64 + ki * 32 + q * 8);
#pragma unroll
            for (int mi = 0; mi < 4; ++mi)
#pragma unroll
                for (int dj = 0; dj < 2; ++dj)
                    o_[mi][dj] = __builtin_amdgcn_mfma_f32_16x16x32_bf16(pa[mi], vb[dj], o_[mi][dj], 0, 0, 0);
        }
    }
    // epilogue
#pragma unroll
    for (int mi = 0; mi < 4; ++mi) {
#pragma unroll
        for (int r = 0; r < 4; ++r) {
            float inv = 1.f / l_[mi][r];
            const int row_local = rowbase + mi * 16 + q * 4 + r;
            __hip_bfloat16* orow = attn_out + (size_t)row_local * KP1 + h * 30;
#pragma unroll
            for (int dj = 0; dj < 2; ++dj) {
                int d = dj * 16 + fr;
                if (d < 30) orow[d] = __float2bfloat16(o_[mi][dj][r] * inv);
            }
        }
    }
    if (h == 0) {
        for (int l = tid; l < 256 * 12; l += 256) {
            int rr2 = l / 12, d = l - rr2 * 12;
            attn_out[(size_t)(wl * 256 + rr2) * KP1 + 180 + d] = __float2bfloat16(0.f);
        }
    }
}

extern "C" void kernel_launch(void* const* d_in, const int* in_sizes, int n_in, void* d_out,
                              int out_size, void* d_ws, size_t ws_size, hipStream_t stream) {
    (void)in_sizes; (void)n_in; (void)out_size; (void)ws_size;
    const float* x = (const float*)d_in[0];
    const int* rpi = (const int*)d_in[3];
    const float* mask = (const float*)d_in[4];
    const float* n1g = (const float*)d_in[5];
    const float* n1b = (const float*)d_in[6];
    const float* qkvw = (const float*)d_in[7];
    const float* qkvb = (const float*)d_in[8];
    const float* rpbt = (const float*)d_in[9];
    const float* projw = (const float*)d_in[10];
    const float* projb = (const float*)d_in[11];
    const float* c1w = (const float*)d_in[12];
    const float* c1b = (const float*)d_in[13];
    const float* c2w = (const float*)d_in[14];
    const float* c2b = (const float*)d_in[15];
    const float* ca1w = (const float*)d_in[16];
    const float* ca1b = (const float*)d_in[17];
    const float* ca2w = (const float*)d_in[18];
    const float* ca2b = (const float*)d_in[19];
    const float* n2g = (const float*)d_in[20];
    const float* n2b = (const float*)d_in[21];
    const float* f1w = (const float*)d_in[22];
    const float* f1b = (const float*)d_in[23];
    const float* f2w = (const float*)d_in[24];
    const float* f2b = (const float*)d_in[25];

    float* ws = (float*)d_ws;
    float* out = (float*)d_out;  // y2 -> x2 -> final output (in place, disjoint phases)

    // workspace layout (floats; every offset multiple of 4 -> 16B aligned)
    float* xn_f     = ws;                    // 6,291,456 (65536x192 bf16)
    float* bufC     = xn_f + 6291456;        // 6,291,456 (y1 bf16 | qkvC+attnC bf16 | h1 bf16)
    float* partials = bufC + 6291456;        // 46,080
    float* scalep   = partials + 46080;      // 192
    float* rpbf     = scalep + 192;          // 393,216
    float* wb1_f    = rpbf + 393216;         // 55,296  (9x64x192 bf16)
    float* wb2_f    = wb1_f + 55296;         // 55,296  (9x192x64 bf16)
    float* qkvbt_f  = wb2_f + 55296;         // 55,296  (576x192 bf16)
    float* projbt_f = qkvbt_f + 55296;       // 18,432  (192x192 bf16)
    float* f1bt_f   = projbt_f + 18432;      // 73,728  (768x192 bf16)
    float* f2bt_f   = f1bt_f + 73728;        // 73,728  (192x768 bf16)

    __hip_bfloat16* xn    = (__hip_bfloat16*)xn_f;
    __hip_bfloat16* y1b   = (__hip_bfloat16*)bufC;                  // 65536x64
    __hip_bfloat16* qkvC  = (__hip_bfloat16*)bufC;                  // 16384x576
    __hip_bfloat16* attnC = (__hip_bfloat16*)(bufC + 4718592);      // 16384x192
    __hip_bfloat16* h1    = (__hip_bfloat16*)bufC;                  // 16384x768
    __hip_bfloat16* wb1    = (__hip_bfloat16*)wb1_f;
    __hip_bfloat16* wb2    = (__hip_bfloat16*)wb2_f;
    __hip_bfloat16* qkvbt  = (__hip_bfloat16*)qkvbt_f;
    __hip_bfloat16* projbt = (__hip_bfloat16*)projbt_f;
    __hip_bfloat16* f1bt   = (__hip_bfloat16*)f1bt_f;
    __hip_bfloat16* f2bt   = (__hip_bfloat16*)f2bt_f;

    // ---- prep ----
    rpb_prep_k<<<256, 256, 0, stream>>>(rpi, rpbt, rpbf);
    wconv_k<<<(9 * 64 * 192 + 255) / 256, 256, 0, stream>>>(c1w, wb1, 60, 180, 64, 192);
    wconv_k<<<(9 * 192 * 64 + 255) / 256, 256, 0, stream>>>(c2w, wb2, 180, 60, 192, 64);
    wprep_k<<<(576 * 192 + 255) / 256, 256, 0, stream>>>(qkvw, qkvbt, 180, 540, 192, 576);
    wprep_k<<<(192 * 192 + 255) / 256, 256, 0, stream>>>(projw, projbt, 180, 180, 192, 192);
    wprep_k<<<(768 * 192 + 255) / 256, 256, 0, stream>>>(f1w, f1bt, 180, 720, 192, 768);
    wprep_k<<<(192 * 768 + 255) / 256, 256, 0, stream>>>(f2w, f2bt, 720, 180, 768, 192);

    // ---- LN1 -> bf16 ----
    ln_k<<<NTOK / 4, 256, 0, stream>>>(x, n1g, n1b, xn);

    // ---- CAB conv branch (MFMA): y2 lives in d_out ----
    mconv_k<192, 60, 64, 1, 1><<<dim3(256, 1), 256, 0, stream>>>(xn, 192, wb1, c1b, y1b);
    mconv_k<64, 180, 180, 0, 0><<<dim3(256, 3), 256, 0, stream>>>(y1b, 64, wb2, c2b, out);
    chansum_k<<<256, 192, 0, stream>>>(out, partials);
    ca_k<<<1, 256, 0, stream>>>(partials, ca1w, ca1b, ca2w, ca2b, scalep);

    // ---- attention branch, 4 chunks of 64 windows; proj epilogue fuses the merge ----
    for (int ck = 0; ck < 4; ++ck) {
        const int rowoff = ck * RCHUNK;
        mgemm_k<3><<<dim3(9, RCHUNK / 128), 256, 0, stream>>>(
            (const unsigned short*)xn, (const unsigned short*)qkvbt, qkvb, nullptr, nullptr,
            qkvC, 192, 540, 576, rowoff);
        attn2_k<<<dim3(64, 6), 256, 0, stream>>>(qkvC, rpbf, mask, attnC, ck * 64);
        mgemm_k<4><<<dim3(3, RCHUNK / 128), 256, 0, stream>>>(
            (const unsigned short*)attnC, (const unsigned short*)projbt, projb, x, scalep,
            out, 192, 180, 180, rowoff);
    }

    // ---- LN2 (x2 in d_out) -> bf16 xm ----
    ln_k<<<NTOK / 4, 256, 0, stream>>>(out, n2g, n2b, xn);

    // ---- MLP, 4 chunks; fc2 adds residual and overwrites d_out in place ----
    for (int ck = 0; ck < 4; ++ck) {
        const int rowoff = ck * RCHUNK;
        mgemm_k<1><<<dim3(12, RCHUNK / 128), 256, 0, stream>>>(
            (const unsigned short*)(xn + (size_t)rowoff * KP1), (const unsigned short*)f1bt,
            f1b, nullptr, nullptr, h1, 192, 720, 768, 0);
        mgemm_k<2><<<dim3(3, RCHUNK / 128), 256, 0, stream>>>(
            (const unsigned short*)h1, (const unsigned short*)f2bt, f2b,
            out + (size_t)rowoff * 180, nullptr, out + (size_t)rowoff * 180, 768, 180, 180, 0);
    }
}

// Round 5
// 1057.450 us; speedup vs baseline: 3.7959x; 1.0203x over previous
//
#include <hip/hip_runtime.h>
#include <hip/hip_bf16.h>
#include <math.h>

#define NTOK 65536
#define C 180
#define KP1 192      // padded K for C=180
#define RCHUNK 16384 // rows per chunk (64 windows)

typedef __attribute__((ext_vector_type(8))) __bf16 bf16x8;
typedef __attribute__((ext_vector_type(4))) float floatx4;

__device__ __forceinline__ float gelu_f(float v) {
    return 0.5f * v * (1.f + erff(v * 0.7071067811865475f));
}
__device__ __forceinline__ float bflo(unsigned int u) { return __uint_as_float(u << 16); }
__device__ __forceinline__ float bfhi(unsigned int u) { return __uint_as_float(u & 0xffff0000u); }

// window-row (shifted-window order) -> pixel row index in [0, 65536)
__device__ __forceinline__ int win2pix(int wrow) {
    int wi = wrow >> 8, ni = wrow & 255;
    int r2 = ((wi >> 4) << 4) | (ni >> 4);
    int c2 = ((wi & 15) << 4) | (ni & 15);
    int r = (r2 + 8) & 255, c = (c2 + 8) & 255;
    return (r << 8) | c;
}

// ---------------- LayerNorm: fp32 in (stride 180) -> bf16 out (stride 192, zero pad) -----------
__global__ __launch_bounds__(256) void ln_k(const float* __restrict__ x,
                                            const float* __restrict__ g,
                                            const float* __restrict__ b,
                                            __hip_bfloat16* __restrict__ y) {
    const int wav = threadIdx.x >> 6;
    const int lane = threadIdx.x & 63;
    const int row = blockIdx.x * 4 + wav;
    const float* xr = x + (size_t)row * C;
    float v0 = xr[lane];
    float v1 = xr[lane + 64];
    float v2 = (lane < C - 128) ? xr[lane + 128] : 0.f;
    float sum = v0 + v1 + v2;
    float sq = v0 * v0 + v1 * v1 + v2 * v2;
#pragma unroll
    for (int off = 32; off >= 1; off >>= 1) {
        sum += __shfl_xor(sum, off, 64);
        sq += __shfl_xor(sq, off, 64);
    }
    const float mu = sum * (1.f / C);
    const float var = sq * (1.f / C) - mu * mu;
    const float rstd = rsqrtf(var + 1e-5f);
    __hip_bfloat16* yr = y + (size_t)row * KP1;
#pragma unroll
    for (int e = 0; e < 3; ++e) {
        int col = lane + 64 * e;
        float val = 0.f;
        if (col < C) {
            float vv = (e == 0) ? v0 : (e == 1 ? v1 : v2);
            val = (vv - mu) * rstd * g[col] + b[col];
        }
        yr[col] = __float2bfloat16(val);
    }
}

// ---------------- conv weight pack: OIHW f32 -> bf16 [tap][oc(OCP)][ch(KP)] zero-padded --------
__global__ void wconv_k(const float* __restrict__ w, __hip_bfloat16* __restrict__ wb,
                        int O, int I, int OCP, int KP) {
    int idx = blockIdx.x * 256 + threadIdx.x;
    if (idx >= 9 * OCP * KP) return;
    int tap = idx / (OCP * KP);
    int rem = idx - tap * (OCP * KP);
    int oc = rem / KP, ch = rem - oc * KP;
    float v = (oc < O && ch < I) ? w[((size_t)(oc * I + ch)) * 9 + tap] : 0.f;
    wb[idx] = __float2bfloat16(v);
}

// ---------------- GEMM weight prep: fp32 [K][N] -> bf16 B^T [NP][KPd] zero-padded --------------
__global__ void wprep_k(const float* __restrict__ w, __hip_bfloat16* __restrict__ bt,
                        int K, int N, int KPd, int NP) {
    int idx = blockIdx.x * 256 + threadIdx.x;
    if (idx >= NP * KPd) return;
    int n = idx / KPd, k = idx - n * KPd;
    float v = (n < N && k < K) ? w[(size_t)k * N + n] : 0.f;
    bt[idx] = __float2bfloat16(v);
}

// ---------------- rpb transposed gather: rpbT[h][col][row] bf16 ----------------
__global__ void rpbt_prep_k(const int* __restrict__ rpi, const float* __restrict__ table,
                            __hip_bfloat16* __restrict__ rpbT) {
    int idx = blockIdx.x * 256 + threadIdx.x;  // 65536 = col*256+row
    int col = idx >> 8, row = idx & 255;
    int t = rpi[row * 256 + col];
#pragma unroll
    for (int h = 0; h < 6; ++h) rpbT[h * 65536 + idx] = __float2bfloat16(table[t * 6 + h]);
}

// ---------------- MFMA implicit-GEMM conv 3x3, NHWC bf16 in, pad 1 ----------------
template <int CINP, int COUT, int OSTR, int ACT, int OUTBF>
__global__ __launch_bounds__(256) void mconv_k(const __hip_bfloat16* __restrict__ in, int istr,
                                               const __hip_bfloat16* __restrict__ wb,
                                               const float* __restrict__ bias,
                                               void* __restrict__ outp) {
    __shared__ __hip_bfloat16 sP[324 * 40];
    __shared__ __hip_bfloat16 sW[9 * 64 * 40];
    const int tid = threadIdx.x;
    const int tr0 = (blockIdx.x >> 4) * 16, tc0 = (blockIdx.x & 15) * 16;
    const int ocbase = blockIdx.y * 64;
    const int w = tid >> 6, lane = tid & 63, fr = lane & 15, q = lane >> 4;
    constexpr int OCP = ((COUT + 63) / 64) * 64;
    floatx4 acc[4][4] = {};
    for (int c0 = 0; c0 < CINP; c0 += 32) {
        for (int l = tid; l < 324 * 4; l += 256) {
            int pos = l >> 2, part = l & 3;
            int pr = pos / 18, pc = pos - pr * 18;
            int gr = tr0 + pr - 1, gc = tc0 + pc - 1;
            float4 v = make_float4(0.f, 0.f, 0.f, 0.f);
            if (gr >= 0 && gr < 256 && gc >= 0 && gc < 256)
                v = *(const float4*)(in + (size_t)(gr * 256 + gc) * istr + c0 + part * 8);
            *(float4*)(sP + pos * 40 + part * 8) = v;
        }
        for (int l = tid; l < 9 * 64 * 4; l += 256) {
            int part = l & 3, oc = (l >> 2) & 63, tap = l >> 8;
            *(float4*)(sW + tap * 2560 + oc * 40 + part * 8) =
                *(const float4*)(wb + (size_t)(tap * OCP + ocbase + oc) * CINP + c0 + part * 8);
        }
        __syncthreads();
#pragma unroll
        for (int tap = 0; tap < 9; ++tap) {
            const int dy = tap / 3, dx = tap - 3 * (tap / 3);
            bf16x8 af[4], bw[4];
#pragma unroll
            for (int mi = 0; mi < 4; ++mi) {
                int pr = 4 * w + mi + dy, pc = fr + dx;
                af[mi] = *(const bf16x8*)(sP + (pr * 18 + pc) * 40 + q * 8);
            }
#pragma unroll
            for (int nj = 0; nj < 4; ++nj)
                bw[nj] = *(const bf16x8*)(sW + tap * 2560 + (nj * 16 + fr) * 40 + q * 8);
#pragma unroll
            for (int mi = 0; mi < 4; ++mi)
#pragma unroll
                for (int nj = 0; nj < 4; ++nj)
                    acc[mi][nj] =
                        __builtin_amdgcn_mfma_f32_16x16x32_bf16(af[mi], bw[nj], acc[mi][nj], 0, 0, 0);
        }
        __syncthreads();
    }
#pragma unroll
    for (int mi = 0; mi < 4; ++mi) {
#pragma unroll
        for (int r = 0; r < 4; ++r) {
            const int irow = tr0 + 4 * w + mi;
            const int icol = tc0 + q * 4 + r;
            const size_t obase = (size_t)(irow * 256 + icol) * OSTR + ocbase;
#pragma unroll
            for (int nj = 0; nj < 4; ++nj) {
                int oc = ocbase + nj * 16 + fr;
                float bv = (oc < COUT) ? bias[oc] : 0.f;
                float v = acc[mi][nj][r] + bv;
                if (ACT) v = gelu_f(v);
                if (OUTBF) {
                    ((__hip_bfloat16*)outp)[obase + nj * 16 + fr] = __float2bfloat16(v);
                } else {
                    if (oc < COUT) ((float*)outp)[obase + nj * 16 + fr] = v;
                }
            }
        }
    }
}

// ---------------- channel sums ----------------
__global__ __launch_bounds__(192) void chansum_k(const float* __restrict__ y2,
                                                 float* __restrict__ partials) {
    const int tid = threadIdx.x;
    if (tid >= C) return;
    const size_t base = (size_t)blockIdx.x * 256 * C;
    float s = 0.f;
    for (int p = 0; p < 256; ++p) s += y2[base + (size_t)p * C + tid];
    partials[blockIdx.x * C + tid] = s;
}

// ---------------- channel attention MLP (1 block) ----------------
__global__ __launch_bounds__(256) void ca_k(const float* __restrict__ partials,
                                            const float* __restrict__ w1, const float* __restrict__ b1,
                                            const float* __restrict__ w2, const float* __restrict__ b2,
                                            float* __restrict__ scale) {
    __shared__ float mean[C];
    __shared__ float s1[6];
    const int tid = threadIdx.x;
    if (tid < C) {
        float s = 0.f;
        for (int b_ = 0; b_ < 256; ++b_) s += partials[b_ * C + tid];
        mean[tid] = s * (1.f / 65536.f);
    }
    __syncthreads();
    if (tid < 6) {
        float s = b1[tid];
        for (int ch = 0; ch < C; ++ch) s += mean[ch] * w1[tid * C + ch];
        s1[tid] = fmaxf(s, 0.f);
    }
    __syncthreads();
    if (tid < C) {
        float s = b2[tid];
#pragma unroll
        for (int j = 0; j < 6; ++j) s += s1[j] * w2[tid * 6 + j];
        scale[tid] = 1.f / (1.f + __expf(-s));
    }
}

// ---------------- bf16 MFMA GEMM: BM=128, BN in {64,128}, BK=32, 4 waves (2x2) ----------
// MODE 1 fc1: bf16 = gelu(A*B+bias), zero for col>=N, written for col<cstride
// MODE 2 fc2: f32  = A*B+bias+xres (col<N)
// MODE 3 qkv: A rows via win2pix; bf16 out, zero for col>=N, written for col<cstride
// MODE 4 proj: f32 at win2pix rows: xres[o] + (A*B+bias) + Cout[o]*scale[col]*0.01
template <int MODE, int BN>
__global__ __launch_bounds__(256) void mgemm_k(const unsigned short* __restrict__ A,
                                               const unsigned short* __restrict__ BT,
                                               const float* __restrict__ bias,
                                               const float* __restrict__ xres,
                                               const float* __restrict__ scale,
                                               void* __restrict__ Cout,
                                               int KPd, int N, int cstride, int rowoff) {
    __shared__ unsigned short As[128 * 40];
    __shared__ unsigned short Bs[BN * 40];
    constexpr int NJ = BN / 32;
    const int tid = threadIdx.x;
    const int m0 = blockIdx.y * 128, n0 = blockIdx.x * BN;
    const int arow_l = tid >> 1;
    const int akofs = (tid & 1) * 16;
    size_t arow;
    if (MODE == 3)
        arow = (size_t)win2pix(rowoff + m0 + arow_l) * KPd;
    else
        arow = (size_t)(m0 + arow_l) * KPd;
    const int brow_l = (BN == 128) ? (tid >> 1) : (tid >> 2);
    const int bkofs = (BN == 128) ? ((tid & 1) * 16) : ((tid & 3) * 8);
    const size_t brow = (size_t)(n0 + brow_l) * KPd;
    const int wave = tid >> 6, lane = tid & 63;
    const int wm = (wave & 1) * 64, wn = (wave >> 1) * (BN / 2);
    const int fr = lane & 15, q = lane >> 4;
    floatx4 acc[4][NJ] = {};
    for (int k0 = 0; k0 < KPd; k0 += 32) {
        *(float4*)(&As[arow_l * 40 + akofs]) = *(const float4*)(A + arow + k0 + akofs);
        *(float4*)(&As[arow_l * 40 + akofs + 8]) = *(const float4*)(A + arow + k0 + akofs + 8);
        if (BN == 128) {
            *(float4*)(&Bs[brow_l * 40 + bkofs]) = *(const float4*)(BT + brow + k0 + bkofs);
            *(float4*)(&Bs[brow_l * 40 + bkofs + 8]) = *(const float4*)(BT + brow + k0 + bkofs + 8);
        } else {
            *(float4*)(&Bs[brow_l * 40 + bkofs]) = *(const float4*)(BT + brow + k0 + bkofs);
        }
        __syncthreads();
        bf16x8 af[4], fB[NJ];
#pragma unroll
        for (int i = 0; i < 4; ++i)
            af[i] = *(const bf16x8*)(&As[(wm + i * 16 + fr) * 40 + q * 8]);
#pragma unroll
        for (int j = 0; j < NJ; ++j)
            fB[j] = *(const bf16x8*)(&Bs[(wn + j * 16 + fr) * 40 + q * 8]);
#pragma unroll
        for (int i = 0; i < 4; ++i)
#pragma unroll
            for (int j = 0; j < NJ; ++j)
                acc[i][j] = __builtin_amdgcn_mfma_f32_16x16x32_bf16(af[i], fB[j], acc[i][j], 0, 0, 0);
        __syncthreads();
    }
#pragma unroll
    for (int i = 0; i < 4; ++i) {
#pragma unroll
        for (int r = 0; r < 4; ++r) {
            const int grow = m0 + wm + i * 16 + q * 4 + r;
            int pix = 0;
            if (MODE == 4) pix = win2pix(rowoff + grow);
#pragma unroll
            for (int j = 0; j < NJ; ++j) {
                const int col = n0 + wn + j * 16 + fr;
                float v = acc[i][j][r];
                if (MODE == 1 || MODE == 3) {
                    if (col < cstride) {
                        float vv = 0.f;
                        if (col < N) {
                            vv = v + bias[col];
                            if (MODE == 1) vv = gelu_f(vv);
                        }
                        ((__hip_bfloat16*)Cout)[(size_t)grow * cstride + col] = __float2bfloat16(vv);
                    }
                } else if (MODE == 2) {
                    if (col < N) {
                        float* o = (float*)Cout;
                        size_t ix = (size_t)grow * cstride + col;
                        o[ix] = v + bias[col] + xres[ix];
                    }
                } else if (MODE == 4) {
                    if (col < N) {
                        float* o = (float*)Cout;
                        size_t ix = (size_t)pix * 180 + col;
                        o[ix] = xres[ix] + v + bias[col] + o[ix] * scale[col] * 0.01f;
                    }
                }
            }
        }
    }
}

// ---------------- MFMA flash attention v3: block per (window, head), 4 waves x 64 q-rows ------
// single-pass exp (no max subtraction: |scores| << 80), vectorized bias, interior mask skip
__global__ __launch_bounds__(256) void attn3_k(const __hip_bfloat16* __restrict__ qkv,  // [16384][576]
                                               const __hip_bfloat16* __restrict__ rpbT, // [h][col][row]
                                               const float* __restrict__ mask,          // [wig][.][.] sym
                                               __hip_bfloat16* __restrict__ attn_out,   // [16384][192]
                                               int wbase) {
    const int wl = blockIdx.x, h = blockIdx.y;
    const int wig = wbase + wl;
    const bool edge = ((wig >> 4) == 15) || ((wig & 15) == 15);
    const int tid = threadIdx.x;
    const int w = tid >> 6, lane = tid & 63;
    const int fr = lane & 15, q = lane >> 4;
    __shared__ __hip_bfloat16 kk[256 * 40];       // [key][d pad40]
    __shared__ __hip_bfloat16 vT[32 * 264];       // [d][key pad264]
    __shared__ __hip_bfloat16 pbuf[4 * 64 * 72];  // per-wave P buffer

    union UB2 { unsigned int u; __hip_bfloat162 h2; };
    // coalesced K/V staging: consecutive threads read consecutive dwords
    for (int l = tid; l < 256 * 15; l += 256) {
        int key = l / 15, dw = l - key * 15;
        const unsigned int* ks =
            (const unsigned int*)(qkv + (size_t)(wl * 256 + key) * 576 + 180 + h * 30);
        *(unsigned int*)(kk + key * 40 + dw * 2) = ks[dw];
        UB2 vv; vv.u = ks[90 + dw];
        vT[(2 * dw) * 264 + key] = vv.h2.x;
        vT[(2 * dw + 1) * 264 + key] = vv.h2.y;
    }
    *(unsigned int*)(kk + tid * 40 + 30) = 0u;  // zero d=30,31 (K-dim pad)
    __syncthreads();

    // Q fragments (raw; scale folded into bias FMA)
    const int rowbase = wl * 256 + w * 64;
    union U8 { unsigned int u[4]; bf16x8 v; };
    bf16x8 qf[4];
#pragma unroll
    for (int mi = 0; mi < 4; ++mi) {
        const unsigned int* p32 =
            (const unsigned int*)(qkv + (size_t)(rowbase + mi * 16 + fr) * 576 + h * 30);
        U8 t;
#pragma unroll
        for (int jj = 0; jj < 4; ++jj) t.u[jj] = p32[q * 4 + jj];
        qf[mi] = t.v;
    }

    const float SC = 0.18257418583505536f;
    float lsum[4][4] = {};
    floatx4 o_[4][2] = {};
    __hip_bfloat16* pb = pbuf + w * 4608;
    const __hip_bfloat16* rpbh = rpbT + (size_t)h * 65536;
    const float* maskw = mask + (size_t)wig * 65536;

    for (int nc = 0; nc < 4; ++nc) {
        bf16x8 kf[4];
#pragma unroll
        for (int nj = 0; nj < 4; ++nj)
            kf[nj] = *(const bf16x8*)(kk + (nc * 64 + nj * 16 + fr) * 40 + q * 8);
        floatx4 s_[4][4] = {};
#pragma unroll
        for (int mi = 0; mi < 4; ++mi)
#pragma unroll
            for (int nj = 0; nj < 4; ++nj)
                s_[mi][nj] = __builtin_amdgcn_mfma_f32_16x16x32_bf16(qf[mi], kf[nj], s_[mi][nj], 0, 0, 0);
        // bias (vectorized via transposed layouts) + exp, accumulate row sums
#pragma unroll
        for (int mi = 0; mi < 4; ++mi) {
            const int rb4 = w * 64 + mi * 16 + q * 4;
#pragma unroll
            for (int nj = 0; nj < 4; ++nj) {
                const int col = nc * 64 + nj * 16 + fr;
                uint2 rb = *(const uint2*)(rpbh + (size_t)col * 256 + rb4);
                float b0 = bflo(rb.x), b1 = bfhi(rb.x), b2 = bflo(rb.y), b3 = bfhi(rb.y);
                if (edge) {
                    float4 mv = *(const float4*)(maskw + (size_t)col * 256 + rb4);
                    b0 += mv.x; b1 += mv.y; b2 += mv.z; b3 += mv.w;
                }
                float p0 = __expf(fmaf(s_[mi][nj][0], SC, b0));
                float p1 = __expf(fmaf(s_[mi][nj][1], SC, b1));
                float p2 = __expf(fmaf(s_[mi][nj][2], SC, b2));
                float p3 = __expf(fmaf(s_[mi][nj][3], SC, b3));
                s_[mi][nj][0] = p0; s_[mi][nj][1] = p1;
                s_[mi][nj][2] = p2; s_[mi][nj][3] = p3;
                lsum[mi][0] += p0; lsum[mi][1] += p1;
                lsum[mi][2] += p2; lsum[mi][3] += p3;
            }
        }
        // P -> per-wave LDS (C-layout scatter), PV via MFMA against vT
#pragma unroll
        for (int mi = 0; mi < 4; ++mi)
#pragma unroll
            for (int nj = 0; nj < 4; ++nj)
#pragma unroll
                for (int r = 0; r < 4; ++r)
                    pb[(mi * 16 + q * 4 + r) * 72 + nj * 16 + fr] = __float2bfloat16(s_[mi][nj][r]);
#pragma unroll
        for (int kc = 0; kc < 2; ++kc) {
            bf16x8 pa[4], vb[2];
#pragma unroll
            for (int mi = 0; mi < 4; ++mi)
                pa[mi] = *(const bf16x8*)(pb + (mi * 16 + fr) * 72 + kc * 32 + q * 8);
#pragma unroll
            for (int dj = 0; dj < 2; ++dj)
                vb[dj] = *(const bf16x8*)(vT + (dj * 16 + fr) * 264 + nc * 64 + kc * 32 + q * 8);
#pragma unroll
            for (int mi = 0; mi < 4; ++mi)
#pragma unroll
                for (int dj = 0; dj < 2; ++dj)
                    o_[mi][dj] = __builtin_amdgcn_mfma_f32_16x16x32_bf16(pa[mi], vb[dj], o_[mi][dj], 0, 0, 0);
        }
    }
    // epilogue: one row-sum reduction, normalize, store
#pragma unroll
    for (int mi = 0; mi < 4; ++mi) {
#pragma unroll
        for (int r = 0; r < 4; ++r) {
            float s = lsum[mi][r];
#pragma unroll
            for (int off = 1; off <= 8; off <<= 1) s += __shfl_xor(s, off, 64);
            float inv = 1.f / s;
            const int row_local = rowbase + mi * 16 + q * 4 + r;
            __hip_bfloat16* orow = attn_out + (size_t)row_local * KP1 + h * 30;
#pragma unroll
            for (int dj = 0; dj < 2; ++dj) {
                int d = dj * 16 + fr;
                if (d < 30) orow[d] = __float2bfloat16(o_[mi][dj][r] * inv);
            }
        }
    }
    if (h == 0) {
        for (int l = tid; l < 256 * 12; l += 256) {
            int rr2 = l / 12, d = l - rr2 * 12;
            attn_out[(size_t)(wl * 256 + rr2) * KP1 + 180 + d] = __float2bfloat16(0.f);
        }
    }
}

extern "C" void kernel_launch(void* const* d_in, const int* in_sizes, int n_in, void* d_out,
                              int out_size, void* d_ws, size_t ws_size, hipStream_t stream) {
    (void)in_sizes; (void)n_in; (void)out_size; (void)ws_size;
    const float* x = (const float*)d_in[0];
    const int* rpi = (const int*)d_in[3];
    const float* mask = (const float*)d_in[4];
    const float* n1g = (const float*)d_in[5];
    const float* n1b = (const float*)d_in[6];
    const float* qkvw = (const float*)d_in[7];
    const float* qkvb = (const float*)d_in[8];
    const float* rpbt = (const float*)d_in[9];
    const float* projw = (const float*)d_in[10];
    const float* projb = (const float*)d_in[11];
    const float* c1w = (const float*)d_in[12];
    const float* c1b = (const float*)d_in[13];
    const float* c2w = (const float*)d_in[14];
    const float* c2b = (const float*)d_in[15];
    const float* ca1w = (const float*)d_in[16];
    const float* ca1b = (const float*)d_in[17];
    const float* ca2w = (const float*)d_in[18];
    const float* ca2b = (const float*)d_in[19];
    const float* n2g = (const float*)d_in[20];
    const float* n2b = (const float*)d_in[21];
    const float* f1w = (const float*)d_in[22];
    const float* f1b = (const float*)d_in[23];
    const float* f2w = (const float*)d_in[24];
    const float* f2b = (const float*)d_in[25];

    float* ws = (float*)d_ws;
    float* out = (float*)d_out;  // y2 -> x2 -> final output (in place, disjoint phases)

    // workspace layout (floats; offsets 16B-aligned). ~53 MB total.
    float* xn_f     = ws;                    // 6,291,456 (65536x192 bf16)
    float* bufC     = xn_f + 6291456;        // 6,291,456 (y1 bf16 | qkvC+attnC bf16 | h1 bf16)
    float* partials = bufC + 6291456;        // 46,080
    float* scalep   = partials + 46080;      // 192
    float* rpbT_f   = scalep + 192;          // 196,608 (6x65536 bf16)
    float* wb1_f    = rpbT_f + 196608;       // 55,296
    float* wb2_f    = wb1_f + 55296;         // 55,296
    float* qkvbt_f  = wb2_f + 55296;         // 61,440  (640x192 bf16)
    float* projbt_f = qkvbt_f + 61440;       // 18,432  (192x192 bf16)
    float* f1bt_f   = projbt_f + 18432;      // 73,728  (768x192 bf16)
    float* f2bt_f   = f1bt_f + 73728;        // 73,728  (192x768 bf16)

    __hip_bfloat16* xn    = (__hip_bfloat16*)xn_f;
    __hip_bfloat16* y1b   = (__hip_bfloat16*)bufC;                  // 65536x64
    __hip_bfloat16* qkvC  = (__hip_bfloat16*)bufC;                  // 16384x576
    __hip_bfloat16* attnC = (__hip_bfloat16*)(bufC + 4718592);      // 16384x192
    __hip_bfloat16* h1    = (__hip_bfloat16*)bufC;                  // 16384x768
    __hip_bfloat16* rpbT   = (__hip_bfloat16*)rpbT_f;
    __hip_bfloat16* wb1    = (__hip_bfloat16*)wb1_f;
    __hip_bfloat16* wb2    = (__hip_bfloat16*)wb2_f;
    __hip_bfloat16* qkvbt  = (__hip_bfloat16*)qkvbt_f;
    __hip_bfloat16* projbt = (__hip_bfloat16*)projbt_f;
    __hip_bfloat16* f1bt   = (__hip_bfloat16*)f1bt_f;
    __hip_bfloat16* f2bt   = (__hip_bfloat16*)f2bt_f;

    // ---- prep ----
    rpbt_prep_k<<<256, 256, 0, stream>>>(rpi, rpbt, rpbT);
    wconv_k<<<(9 * 64 * 192 + 255) / 256, 256, 0, stream>>>(c1w, wb1, 60, 180, 64, 192);
    wconv_k<<<(9 * 192 * 64 + 255) / 256, 256, 0, stream>>>(c2w, wb2, 180, 60, 192, 64);
    wprep_k<<<(640 * 192 + 255) / 256, 256, 0, stream>>>(qkvw, qkvbt, 180, 540, 192, 640);
    wprep_k<<<(192 * 192 + 255) / 256, 256, 0, stream>>>(projw, projbt, 180, 180, 192, 192);
    wprep_k<<<(768 * 192 + 255) / 256, 256, 0, stream>>>(f1w, f1bt, 180, 720, 192, 768);
    wprep_k<<<(192 * 768 + 255) / 256, 256, 0, stream>>>(f2w, f2bt, 720, 180, 768, 192);

    // ---- LN1 -> bf16 ----
    ln_k<<<NTOK / 4, 256, 0, stream>>>(x, n1g, n1b, xn);

    // ---- CAB conv branch (MFMA): y2 lives in d_out ----
    mconv_k<192, 60, 64, 1, 1><<<dim3(256, 1), 256, 0, stream>>>(xn, 192, wb1, c1b, y1b);
    mconv_k<64, 180, 180, 0, 0><<<dim3(256, 3), 256, 0, stream>>>(y1b, 64, wb2, c2b, out);
    chansum_k<<<256, 192, 0, stream>>>(out, partials);
    ca_k<<<1, 256, 0, stream>>>(partials, ca1w, ca1b, ca2w, ca2b, scalep);

    // ---- attention branch, 4 chunks of 64 windows; proj epilogue fuses the merge ----
    for (int ck = 0; ck < 4; ++ck) {
        const int rowoff = ck * RCHUNK;
        mgemm_k<3, 128><<<dim3(5, RCHUNK / 128), 256, 0, stream>>>(
            (const unsigned short*)xn, (const unsigned short*)qkvbt, qkvb, nullptr, nullptr,
            qkvC, 192, 540, 576, rowoff);
        attn3_k<<<dim3(64, 6), 256, 0, stream>>>(qkvC, rpbT, mask, attnC, ck * 64);
        mgemm_k<4, 64><<<dim3(3, RCHUNK / 128), 256, 0, stream>>>(
            (const unsigned short*)attnC, (const unsigned short*)projbt, projb, x, scalep,
            out, 192, 180, 180, rowoff);
    }

    // ---- LN2 (x2 in d_out) -> bf16 xm ----
    ln_k<<<NTOK / 4, 256, 0, stream>>>(out, n2g, n2b, xn);

    // ---- MLP, 4 chunks; fc2 adds residual and overwrites d_out in place ----
    for (int ck = 0; ck < 4; ++ck) {
        const int rowoff = ck * RCHUNK;
        mgemm_k<1, 128><<<dim3(6, RCHUNK / 128), 256, 0, stream>>>(
            (const unsigned short*)(xn + (size_t)rowoff * KP1), (const unsigned short*)f1bt,
            f1b, nullptr, nullptr, h1, 192, 720, 768, 0);
        mgemm_k<2, 64><<<dim3(3, RCHUNK / 128), 256, 0, stream>>>(
            (const unsigned short*)h1, (const unsigned short*)f2bt, f2b,
            out + (size_t)rowoff * 180, nullptr, out + (size_t)rowoff * 180, 768, 180, 180, 0);
    }
}

// Round 7
// 881.860 us; speedup vs baseline: 4.5517x; 1.1991x over previous
//
#include <hip/hip_runtime.h>
#include <hip/hip_bf16.h>
#include <math.h>

#define NTOK 65536
#define C 180
#define KP1 192      // padded K for C=180
#define RCHUNK 32768 // rows per chunk (128 windows)

typedef __attribute__((ext_vector_type(8))) __bf16 bf16x8;
typedef __attribute__((ext_vector_type(4))) float floatx4;

__device__ __forceinline__ float gelu_f(float v) {
    return 0.5f * v * (1.f + erff(v * 0.7071067811865475f));
}
__device__ __forceinline__ float bflo(unsigned int u) { return __uint_as_float(u << 16); }
__device__ __forceinline__ float bfhi(unsigned int u) { return __uint_as_float(u & 0xffff0000u); }

// window-row (shifted-window order) -> pixel row index in [0, 65536)
__device__ __forceinline__ int win2pix(int wrow) {
    int wi = wrow >> 8, ni = wrow & 255;
    int r2 = ((wi >> 4) << 4) | (ni >> 4);
    int c2 = ((wi & 15) << 4) | (ni & 15);
    int r = (r2 + 8) & 255, c = (c2 + 8) & 255;
    return (r << 8) | c;
}

// ---------------- LayerNorm: fp32 in (stride 180) -> bf16 out (stride 192, zero pad) -----------
__global__ __launch_bounds__(256) void ln_k(const float* __restrict__ x,
                                            const float* __restrict__ g,
                                            const float* __restrict__ b,
                                            __hip_bfloat16* __restrict__ y) {
    const int wav = threadIdx.x >> 6;
    const int lane = threadIdx.x & 63;
    const int row = blockIdx.x * 4 + wav;
    const float* xr = x + (size_t)row * C;
    float v0 = xr[lane];
    float v1 = xr[lane + 64];
    float v2 = (lane < C - 128) ? xr[lane + 128] : 0.f;
    float sum = v0 + v1 + v2;
    float sq = v0 * v0 + v1 * v1 + v2 * v2;
#pragma unroll
    for (int off = 32; off >= 1; off >>= 1) {
        sum += __shfl_xor(sum, off, 64);
        sq += __shfl_xor(sq, off, 64);
    }
    const float mu = sum * (1.f / C);
    const float var = sq * (1.f / C) - mu * mu;
    const float rstd = rsqrtf(var + 1e-5f);
    __hip_bfloat16* yr = y + (size_t)row * KP1;
#pragma unroll
    for (int e = 0; e < 3; ++e) {
        int col = lane + 64 * e;
        float val = 0.f;
        if (col < C) {
            float vv = (e == 0) ? v0 : (e == 1 ? v1 : v2);
            val = (vv - mu) * rstd * g[col] + b[col];
        }
        yr[col] = __float2bfloat16(val);
    }
}

// ---------------- conv weight pack: OIHW f32 -> bf16 [tap][oc(OCP)][ch(KP)] zero-padded --------
__global__ void wconv_k(const float* __restrict__ w, __hip_bfloat16* __restrict__ wb,
                        int O, int I, int OCP, int KP) {
    int idx = blockIdx.x * 256 + threadIdx.x;
    if (idx >= 9 * OCP * KP) return;
    int tap = idx / (OCP * KP);
    int rem = idx - tap * (OCP * KP);
    int oc = rem / KP, ch = rem - oc * KP;
    float v = (oc < O && ch < I) ? w[((size_t)(oc * I + ch)) * 9 + tap] : 0.f;
    wb[idx] = __float2bfloat16(v);
}

// ---------------- GEMM weight prep: fp32 [K][N] -> bf16 B^T [NP][KPd] zero-padded --------------
__global__ void wprep_k(const float* __restrict__ w, __hip_bfloat16* __restrict__ bt,
                        int K, int N, int KPd, int NP) {
    int idx = blockIdx.x * 256 + threadIdx.x;
    if (idx >= NP * KPd) return;
    int n = idx / KPd, k = idx - n * KPd;
    float v = (n < N && k < K) ? w[(size_t)k * N + n] : 0.f;
    bt[idx] = __float2bfloat16(v);
}

// ---------------- rpb transposed gather: rpbT[h][col][row] bf16 ----------------
__global__ void rpbt_prep_k(const int* __restrict__ rpi, const float* __restrict__ table,
                            __hip_bfloat16* __restrict__ rpbT) {
    int idx = blockIdx.x * 256 + threadIdx.x;  // 65536 = col*256+row
    int col = idx >> 8, row = idx & 255;
    int t = rpi[row * 256 + col];
#pragma unroll
    for (int h = 0; h < 6; ++h) rpbT[h * 65536 + idx] = __float2bfloat16(table[t * 6 + h]);
}

// ---------------- MFMA implicit-GEMM conv 3x3, NHWC bf16 in, pad 1 ----------------
template <int CINP, int COUT, int OSTR, int ACT, int OUTBF>
__global__ __launch_bounds__(256) void mconv_k(const __hip_bfloat16* __restrict__ in, int istr,
                                               const __hip_bfloat16* __restrict__ wb,
                                               const float* __restrict__ bias,
                                               void* __restrict__ outp) {
    __shared__ __hip_bfloat16 sP[324 * 40];
    __shared__ __hip_bfloat16 sW[9 * 64 * 40];
    const int tid = threadIdx.x;
    const int tr0 = (blockIdx.x >> 4) * 16, tc0 = (blockIdx.x & 15) * 16;
    const int ocbase = blockIdx.y * 64;
    const int w = tid >> 6, lane = tid & 63, fr = lane & 15, q = lane >> 4;
    constexpr int OCP = ((COUT + 63) / 64) * 64;
    floatx4 acc[4][4] = {};
    for (int c0 = 0; c0 < CINP; c0 += 32) {
        for (int l = tid; l < 324 * 4; l += 256) {
            int pos = l >> 2, part = l & 3;
            int pr = pos / 18, pc = pos - pr * 18;
            int gr = tr0 + pr - 1, gc = tc0 + pc - 1;
            float4 v = make_float4(0.f, 0.f, 0.f, 0.f);
            if (gr >= 0 && gr < 256 && gc >= 0 && gc < 256)
                v = *(const float4*)(in + (size_t)(gr * 256 + gc) * istr + c0 + part * 8);
            *(float4*)(sP + pos * 40 + part * 8) = v;
        }
        for (int l = tid; l < 9 * 64 * 4; l += 256) {
            int part = l & 3, oc = (l >> 2) & 63, tap = l >> 8;
            *(float4*)(sW + tap * 2560 + oc * 40 + part * 8) =
                *(const float4*)(wb + (size_t)(tap * OCP + ocbase + oc) * CINP + c0 + part * 8);
        }
        __syncthreads();
#pragma unroll
        for (int tap = 0; tap < 9; ++tap) {
            const int dy = tap / 3, dx = tap - 3 * (tap / 3);
            bf16x8 af[4], bw[4];
#pragma unroll
            for (int mi = 0; mi < 4; ++mi) {
                int pr = 4 * w + mi + dy, pc = fr + dx;
                af[mi] = *(const bf16x8*)(sP + (pr * 18 + pc) * 40 + q * 8);
            }
#pragma unroll
            for (int nj = 0; nj < 4; ++nj)
                bw[nj] = *(const bf16x8*)(sW + tap * 2560 + (nj * 16 + fr) * 40 + q * 8);
#pragma unroll
            for (int mi = 0; mi < 4; ++mi)
#pragma unroll
                for (int nj = 0; nj < 4; ++nj)
                    acc[mi][nj] =
                        __builtin_amdgcn_mfma_f32_16x16x32_bf16(af[mi], bw[nj], acc[mi][nj], 0, 0, 0);
        }
        __syncthreads();
    }
#pragma unroll
    for (int mi = 0; mi < 4; ++mi) {
#pragma unroll
        for (int r = 0; r < 4; ++r) {
            const int irow = tr0 + 4 * w + mi;
            const int icol = tc0 + q * 4 + r;
            const size_t obase = (size_t)(irow * 256 + icol) * OSTR + ocbase;
#pragma unroll
            for (int nj = 0; nj < 4; ++nj) {
                int oc = ocbase + nj * 16 + fr;
                float bv = (oc < COUT) ? bias[oc] : 0.f;
                float v = acc[mi][nj][r] + bv;
                if (ACT) v = gelu_f(v);
                if (OUTBF) {
                    ((__hip_bfloat16*)outp)[obase + nj * 16 + fr] = __float2bfloat16(v);
                } else {
                    if (oc < COUT) ((float*)outp)[obase + nj * 16 + fr] = v;
                }
            }
        }
    }
}

// ---------------- channel sums ----------------
__global__ __launch_bounds__(192) void chansum_k(const float* __restrict__ y2,
                                                 float* __restrict__ partials) {
    const int tid = threadIdx.x;
    if (tid >= C) return;
    const size_t base = (size_t)blockIdx.x * 256 * C;
    float s = 0.f;
    for (int p = 0; p < 256; ++p) s += y2[base + (size_t)p * C + tid];
    partials[blockIdx.x * C + tid] = s;
}

// ---------------- channel attention MLP (1 block) ----------------
__global__ __launch_bounds__(256) void ca_k(const float* __restrict__ partials,
                                            const float* __restrict__ w1, const float* __restrict__ b1,
                                            const float* __restrict__ w2, const float* __restrict__ b2,
                                            float* __restrict__ scale) {
    __shared__ float mean[C];
    __shared__ float s1[6];
    const int tid = threadIdx.x;
    if (tid < C) {
        float s = 0.f;
        for (int b_ = 0; b_ < 256; ++b_) s += partials[b_ * C + tid];
        mean[tid] = s * (1.f / 65536.f);
    }
    __syncthreads();
    if (tid < 6) {
        float s = b1[tid];
        for (int ch = 0; ch < C; ++ch) s += mean[ch] * w1[tid * C + ch];
        s1[tid] = fmaxf(s, 0.f);
    }
    __syncthreads();
    if (tid < C) {
        float s = b2[tid];
#pragma unroll
        for (int j = 0; j < 6; ++j) s += s1[j] * w2[tid * 6 + j];
        scale[tid] = 1.f / (1.f + __expf(-s));
    }
}

// ---------------- bf16 MFMA GEMM: BM=128, BN in {64,128}, BK=32, 4 waves (2x2) ----------
// MODE 1 fc1: bf16 = gelu(A*B+bias), zero for col>=N, written for col<cstride
// MODE 2 fc2: f32  = A*B+bias+xres (col<N)
// MODE 3 qkv: A rows via win2pix; bf16 out, zero for col>=N, written for col<cstride
// MODE 4 proj: f32 at win2pix rows: xres[o] + (A*B+bias) + Cout[o]*scale[col]*0.01
template <int MODE, int BN>
__global__ __launch_bounds__(256) void mgemm_k(const unsigned short* __restrict__ A,
                                               const unsigned short* __restrict__ BT,
                                               const float* __restrict__ bias,
                                               const float* __restrict__ xres,
                                               const float* __restrict__ scale,
                                               void* __restrict__ Cout,
                                               int KPd, int N, int cstride, int rowoff) {
    __shared__ unsigned short As[128 * 40];
    __shared__ unsigned short Bs[BN * 40];
    constexpr int NJ = BN / 32;
    const int tid = threadIdx.x;
    const int m0 = blockIdx.y * 128, n0 = blockIdx.x * BN;
    const int arow_l = tid >> 1;
    const int akofs = (tid & 1) * 16;
    size_t arow;
    if (MODE == 3)
        arow = (size_t)win2pix(rowoff + m0 + arow_l) * KPd;
    else
        arow = (size_t)(m0 + arow_l) * KPd;
    const int brow_l = (BN == 128) ? (tid >> 1) : (tid >> 2);
    const int bkofs = (BN == 128) ? ((tid & 1) * 16) : ((tid & 3) * 8);
    const size_t brow = (size_t)(n0 + brow_l) * KPd;
    const int wave = tid >> 6, lane = tid & 63;
    const int wm = (wave & 1) * 64, wn = (wave >> 1) * (BN / 2);
    const int fr = lane & 15, q = lane >> 4;
    floatx4 acc[4][NJ] = {};
    for (int k0 = 0; k0 < KPd; k0 += 32) {
        *(float4*)(&As[arow_l * 40 + akofs]) = *(const float4*)(A + arow + k0 + akofs);
        *(float4*)(&As[arow_l * 40 + akofs + 8]) = *(const float4*)(A + arow + k0 + akofs + 8);
        if (BN == 128) {
            *(float4*)(&Bs[brow_l * 40 + bkofs]) = *(const float4*)(BT + brow + k0 + bkofs);
            *(float4*)(&Bs[brow_l * 40 + bkofs + 8]) = *(const float4*)(BT + brow + k0 + bkofs + 8);
        } else {
            *(float4*)(&Bs[brow_l * 40 + bkofs]) = *(const float4*)(BT + brow + k0 + bkofs);
        }
        __syncthreads();
        bf16x8 af[4], fB[NJ];
#pragma unroll
        for (int i = 0; i < 4; ++i)
            af[i] = *(const bf16x8*)(&As[(wm + i * 16 + fr) * 40 + q * 8]);
#pragma unroll
        for (int j = 0; j < NJ; ++j)
            fB[j] = *(const bf16x8*)(&Bs[(wn + j * 16 + fr) * 40 + q * 8]);
#pragma unroll
        for (int i = 0; i < 4; ++i)
#pragma unroll
            for (int j = 0; j < NJ; ++j)
                acc[i][j] = __builtin_amdgcn_mfma_f32_16x16x32_bf16(af[i], fB[j], acc[i][j], 0, 0, 0);
        __syncthreads();
    }
#pragma unroll
    for (int i = 0; i < 4; ++i) {
#pragma unroll
        for (int r = 0; r < 4; ++r) {
            const int grow = m0 + wm + i * 16 + q * 4 + r;
            int pix = 0;
            if (MODE == 4) pix = win2pix(rowoff + grow);
#pragma unroll
            for (int j = 0; j < NJ; ++j) {
                const int col = n0 + wn + j * 16 + fr;
                float v = acc[i][j][r];
                if (MODE == 1 || MODE == 3) {
                    if (col < cstride) {
                        float vv = 0.f;
                        if (col < N) {
                            vv = v + bias[col];
                            if (MODE == 1) vv = gelu_f(vv);
                        }
                        ((__hip_bfloat16*)Cout)[(size_t)grow * cstride + col] = __float2bfloat16(vv);
                    }
                } else if (MODE == 2) {
                    if (col < N) {
                        float* o = (float*)Cout;
                        size_t ix = (size_t)grow * cstride + col;
                        o[ix] = v + bias[col] + xres[ix];
                    }
                } else if (MODE == 4) {
                    if (col < N) {
                        float* o = (float*)Cout;
                        size_t ix = (size_t)pix * 180 + col;
                        o[ix] = xres[ix] + v + bias[col] + o[ix] * scale[col] * 0.01f;
                    }
                }
            }
        }
    }
}

// ---------------- MFMA flash attention v4: block per (window, head), 4 waves x 64 q-rows ------
// LDS diet: kk stride 32 (contiguous wave reads), half-size P buffer (two 32-key half-steps)
// -> 53,760 B LDS -> 3 blocks/CU
__global__ __launch_bounds__(256) void attn4_k(const __hip_bfloat16* __restrict__ qkv,  // [R][576]
                                               const __hip_bfloat16* __restrict__ rpbT, // [h][col][row]
                                               const float* __restrict__ mask,          // [wig][.][.] sym
                                               __hip_bfloat16* __restrict__ attn_out,   // [R][192]
                                               int wbase) {
    const int wl = blockIdx.x, h = blockIdx.y;
    const int wig = wbase + wl;
    const bool edge = ((wig >> 4) == 15) || ((wig & 15) == 15);
    const int tid = threadIdx.x;
    const int w = tid >> 6, lane = tid & 63;
    const int fr = lane & 15, q = lane >> 4;
    __shared__ __hip_bfloat16 kk[256 * 32];       // [key][d pad32]
    __shared__ __hip_bfloat16 vT[32 * 264];       // [d][key pad264]
    __shared__ __hip_bfloat16 pbuf[4 * 64 * 40];  // per-wave P half-buffer (32 keys + 8 pad)

    union UB2 { unsigned int u; __hip_bfloat162 h2; };
    for (int l = tid; l < 256 * 15; l += 256) {
        int key = l / 15, dw = l - key * 15;
        const unsigned int* ks =
            (const unsigned int*)(qkv + (size_t)(wl * 256 + key) * 576 + 180 + h * 30);
        *(unsigned int*)(kk + key * 32 + dw * 2) = ks[dw];
        UB2 vv; vv.u = ks[90 + dw];
        vT[(2 * dw) * 264 + key] = vv.h2.x;
        vT[(2 * dw + 1) * 264 + key] = vv.h2.y;
    }
    *(unsigned int*)(kk + tid * 32 + 30) = 0u;  // zero d=30,31 (K-dim pad)
    __syncthreads();

    // Q fragments (raw; scale folded into bias FMA)
    const int rowbase = wl * 256 + w * 64;
    union U8 { unsigned int u[4]; bf16x8 v; };
    bf16x8 qf[4];
#pragma unroll
    for (int mi = 0; mi < 4; ++mi) {
        const unsigned int* p32 =
            (const unsigned int*)(qkv + (size_t)(rowbase + mi * 16 + fr) * 576 + h * 30);
        U8 t;
#pragma unroll
        for (int jj = 0; jj < 4; ++jj) t.u[jj] = p32[q * 4 + jj];
        qf[mi] = t.v;
    }

    const float SC = 0.18257418583505536f;
    float lsum[4][4] = {};
    floatx4 o_[4][2] = {};
    __hip_bfloat16* pb = pbuf + w * 2560;
    const __hip_bfloat16* rpbh = rpbT + (size_t)h * 65536;
    const float* maskw = mask + (size_t)wig * 65536;

    for (int nc = 0; nc < 4; ++nc) {
        bf16x8 kf[4];
#pragma unroll
        for (int nj = 0; nj < 4; ++nj)
            kf[nj] = *(const bf16x8*)(kk + (nc * 64 + nj * 16 + fr) * 32 + q * 8);
        floatx4 s_[4][4] = {};
#pragma unroll
        for (int mi = 0; mi < 4; ++mi)
#pragma unroll
            for (int nj = 0; nj < 4; ++nj)
                s_[mi][nj] = __builtin_amdgcn_mfma_f32_16x16x32_bf16(qf[mi], kf[nj], s_[mi][nj], 0, 0, 0);
        // bias (vectorized via transposed layouts) + exp, accumulate row sums
#pragma unroll
        for (int mi = 0; mi < 4; ++mi) {
            const int rb4 = w * 64 + mi * 16 + q * 4;
#pragma unroll
            for (int nj = 0; nj < 4; ++nj) {
                const int col = nc * 64 + nj * 16 + fr;
                uint2 rb = *(const uint2*)(rpbh + (size_t)col * 256 + rb4);
                float b0 = bflo(rb.x), b1 = bfhi(rb.x), b2 = bflo(rb.y), b3 = bfhi(rb.y);
                if (edge) {
                    float4 mv = *(const float4*)(maskw + (size_t)col * 256 + rb4);
                    b0 += mv.x; b1 += mv.y; b2 += mv.z; b3 += mv.w;
                }
                float p0 = __expf(fmaf(s_[mi][nj][0], SC, b0));
                float p1 = __expf(fmaf(s_[mi][nj][1], SC, b1));
                float p2 = __expf(fmaf(s_[mi][nj][2], SC, b2));
                float p3 = __expf(fmaf(s_[mi][nj][3], SC, b3));
                s_[mi][nj][0] = p0; s_[mi][nj][1] = p1;
                s_[mi][nj][2] = p2; s_[mi][nj][3] = p3;
                lsum[mi][0] += p0; lsum[mi][1] += p1;
                lsum[mi][2] += p2; lsum[mi][3] += p3;
            }
        }
        // two 32-key half-steps: P scatter -> PV MFMA (per-wave DS ops are in-order; WAR safe)
#pragma unroll
        for (int kc = 0; kc < 2; ++kc) {
#pragma unroll
            for (int mi = 0; mi < 4; ++mi)
#pragma unroll
                for (int nj = 0; nj < 2; ++nj)
#pragma unroll
                    for (int r = 0; r < 4; ++r)
                        pb[(mi * 16 + q * 4 + r) * 40 + nj * 16 + fr] =
                            __float2bfloat16(s_[mi][kc * 2 + nj][r]);
            bf16x8 pa[4], vb[2];
#pragma unroll
            for (int mi = 0; mi < 4; ++mi)
                pa[mi] = *(const bf16x8*)(pb + (mi * 16 + fr) * 40 + q * 8);
#pragma unroll
            for (int dj = 0; dj < 2; ++dj)
                vb[dj] = *(const bf16x8*)(vT + (dj * 16 + fr) * 264 + nc * 64 + kc * 32 + q * 8);
#pragma unroll
            for (int mi = 0; mi < 4; ++mi)
#pragma unroll
                for (int dj = 0; dj < 2; ++dj)
                    o_[mi][dj] = __builtin_amdgcn_mfma_f32_16x16x32_bf16(pa[mi], vb[dj], o_[mi][dj], 0, 0, 0);
        }
    }
    // epilogue: one row-sum reduction, normalize, store
#pragma unroll
    for (int mi = 0; mi < 4; ++mi) {
#pragma unroll
        for (int r = 0; r < 4; ++r) {
            float s = lsum[mi][r];
#pragma unroll
            for (int off = 1; off <= 8; off <<= 1) s += __shfl_xor(s, off, 64);
            float inv = 1.f / s;
            const int row_local = rowbase + mi * 16 + q * 4 + r;
            __hip_bfloat16* orow = attn_out + (size_t)row_local * KP1 + h * 30;
#pragma unroll
            for (int dj = 0; dj < 2; ++dj) {
                int d = dj * 16 + fr;
                if (d < 30) orow[d] = __float2bfloat16(o_[mi][dj][r] * inv);
            }
        }
    }
    if (h == 0) {
        for (int l = tid; l < 256 * 12; l += 256) {
            int rr2 = l / 12, d = l - rr2 * 12;
            attn_out[(size_t)(wl * 256 + rr2) * KP1 + 180 + d] = __float2bfloat16(0.f);
        }
    }
}

extern "C" void kernel_launch(void* const* d_in, const int* in_sizes, int n_in, void* d_out,
                              int out_size, void* d_ws, size_t ws_size, hipStream_t stream) {
    (void)in_sizes; (void)n_in; (void)out_size; (void)ws_size;
    const float* x = (const float*)d_in[0];
    const int* rpi = (const int*)d_in[3];
    const float* mask = (const float*)d_in[4];
    const float* n1g = (const float*)d_in[5];
    const float* n1b = (const float*)d_in[6];
    const float* qkvw = (const float*)d_in[7];
    const float* qkvb = (const float*)d_in[8];
    const float* rpbt = (const float*)d_in[9];
    const float* projw = (const float*)d_in[10];
    const float* projb = (const float*)d_in[11];
    const float* c1w = (const float*)d_in[12];
    const float* c1b = (const float*)d_in[13];
    const float* c2w = (const float*)d_in[14];
    const float* c2b = (const float*)d_in[15];
    const float* ca1w = (const float*)d_in[16];
    const float* ca1b = (const float*)d_in[17];
    const float* ca2w = (const float*)d_in[18];
    const float* ca2b = (const float*)d_in[19];
    const float* n2g = (const float*)d_in[20];
    const float* n2b = (const float*)d_in[21];
    const float* f1w = (const float*)d_in[22];
    const float* f1b = (const float*)d_in[23];
    const float* f2w = (const float*)d_in[24];
    const float* f2b = (const float*)d_in[25];

    float* ws = (float*)d_ws;
    float* out = (float*)d_out;  // y2 -> x2 -> final output (in place, disjoint phases)

    // workspace layout (floats; offsets 16B-aligned). ~77.8 MB total.
    float* xn_f     = ws;                    // 6,291,456 (65536x192 bf16)
    float* bufC     = xn_f + 6291456;        // 12,582,912 (y1b | qkvC+attnC | h1, all bf16)
    float* partials = bufC + 12582912;       // 46,080
    float* scalep   = partials + 46080;      // 192
    float* rpbT_f   = scalep + 192;          // 196,608 (6x65536 bf16)
    float* wb1_f    = rpbT_f + 196608;       // 55,296
    float* wb2_f    = wb1_f + 55296;         // 55,296
    float* qkvbt_f  = wb2_f + 55296;         // 61,440  (640x192 bf16)
    float* projbt_f = qkvbt_f + 61440;       // 18,432  (192x192 bf16)
    float* f1bt_f   = projbt_f + 18432;      // 73,728  (768x192 bf16)
    float* f2bt_f   = f1bt_f + 73728;        // 73,728  (192x768 bf16)

    __hip_bfloat16* xn    = (__hip_bfloat16*)xn_f;
    __hip_bfloat16* y1b   = (__hip_bfloat16*)bufC;                  // 65536x64
    __hip_bfloat16* qkvC  = (__hip_bfloat16*)bufC;                  // 32768x576
    __hip_bfloat16* attnC = (__hip_bfloat16*)(bufC + 9437184);      // 32768x192
    __hip_bfloat16* h1    = (__hip_bfloat16*)bufC;                  // 32768x768
    __hip_bfloat16* rpbT   = (__hip_bfloat16*)rpbT_f;
    __hip_bfloat16* wb1    = (__hip_bfloat16*)wb1_f;
    __hip_bfloat16* wb2    = (__hip_bfloat16*)wb2_f;
    __hip_bfloat16* qkvbt  = (__hip_bfloat16*)qkvbt_f;
    __hip_bfloat16* projbt = (__hip_bfloat16*)projbt_f;
    __hip_bfloat16* f1bt   = (__hip_bfloat16*)f1bt_f;
    __hip_bfloat16* f2bt   = (__hip_bfloat16*)f2bt_f;

    // ---- prep ----
    rpbt_prep_k<<<256, 256, 0, stream>>>(rpi, rpbt, rpbT);
    wconv_k<<<(9 * 64 * 192 + 255) / 256, 256, 0, stream>>>(c1w, wb1, 60, 180, 64, 192);
    wconv_k<<<(9 * 192 * 64 + 255) / 256, 256, 0, stream>>>(c2w, wb2, 180, 60, 192, 64);
    wprep_k<<<(640 * 192 + 255) / 256, 256, 0, stream>>>(qkvw, qkvbt, 180, 540, 192, 640);
    wprep_k<<<(192 * 192 + 255) / 256, 256, 0, stream>>>(projw, projbt, 180, 180, 192, 192);
    wprep_k<<<(768 * 192 + 255) / 256, 256, 0, stream>>>(f1w, f1bt, 180, 720, 192, 768);
    wprep_k<<<(192 * 768 + 255) / 256, 256, 0, stream>>>(f2w, f2bt, 720, 180, 768, 192);

    // ---- LN1 -> bf16 ----
    ln_k<<<NTOK / 4, 256, 0, stream>>>(x, n1g, n1b, xn);

    // ---- CAB conv branch (MFMA): y2 lives in d_out ----
    mconv_k<192, 60, 64, 1, 1><<<dim3(256, 1), 256, 0, stream>>>(xn, 192, wb1, c1b, y1b);
    mconv_k<64, 180, 180, 0, 0><<<dim3(256, 3), 256, 0, stream>>>(y1b, 64, wb2, c2b, out);
    chansum_k<<<256, 192, 0, stream>>>(out, partials);
    ca_k<<<1, 256, 0, stream>>>(partials, ca1w, ca1b, ca2w, ca2b, scalep);

    // ---- attention branch, 2 chunks of 128 windows; proj epilogue fuses the merge ----
    for (int ck = 0; ck < 2; ++ck) {
        const int rowoff = ck * RCHUNK;
        mgemm_k<3, 128><<<dim3(5, RCHUNK / 128), 256, 0, stream>>>(
            (const unsigned short*)xn, (const unsigned short*)qkvbt, qkvb, nullptr, nullptr,
            qkvC, 192, 540, 576, rowoff);
        attn4_k<<<dim3(128, 6), 256, 0, stream>>>(qkvC, rpbT, mask, attnC, ck * 128);
        mgemm_k<4, 64><<<dim3(3, RCHUNK / 128), 256, 0, stream>>>(
            (const unsigned short*)attnC, (const unsigned short*)projbt, projb, x, scalep,
            out, 192, 180, 180, rowoff);
    }

    // ---- LN2 (x2 in d_out) -> bf16 xm ----
    ln_k<<<NTOK / 4, 256, 0, stream>>>(out, n2g, n2b, xn);

    // ---- MLP, 2 chunks; fc2 adds residual and overwrites d_out in place ----
    for (int ck = 0; ck < 2; ++ck) {
        const int rowoff = ck * RCHUNK;
        mgemm_k<1, 128><<<dim3(6, RCHUNK / 128), 256, 0, stream>>>(
            (const unsigned short*)(xn + (size_t)rowoff * KP1), (const unsigned short*)f1bt,
            f1b, nullptr, nullptr, h1, 192, 720, 768, 0);
        mgemm_k<2, 64><<<dim3(3, RCHUNK / 128), 256, 0, stream>>>(
            (const unsigned short*)h1, (const unsigned short*)f2bt, f2b,
            out + (size_t)rowoff * 180, nullptr, out + (size_t)rowoff * 180, 768, 180, 180, 0);
    }
}

// Round 8
// 834.640 us; speedup vs baseline: 4.8092x; 1.0566x over previous
//
#include <hip/hip_runtime.h>
#include <hip/hip_bf16.h>
#include <math.h>

#define NTOK 65536
#define C 180
#define KP1 192      // padded K for C=180
#define RCHUNK 32768 // rows per chunk (128 windows)

typedef __attribute__((ext_vector_type(8))) __bf16 bf16x8;
typedef __attribute__((ext_vector_type(4))) float floatx4;

__device__ __forceinline__ float gelu_f(float v) {
    return 0.5f * v * (1.f + erff(v * 0.7071067811865475f));
}
__device__ __forceinline__ float bflo(unsigned int u) { return __uint_as_float(u << 16); }
__device__ __forceinline__ float bfhi(unsigned int u) { return __uint_as_float(u & 0xffff0000u); }

// window-row (shifted-window order) -> pixel row index in [0, 65536)
__device__ __forceinline__ int win2pix(int wrow) {
    int wi = wrow >> 8, ni = wrow & 255;
    int r2 = ((wi >> 4) << 4) | (ni >> 4);
    int c2 = ((wi & 15) << 4) | (ni & 15);
    int r = (r2 + 8) & 255, c = (c2 + 8) & 255;
    return (r << 8) | c;
}

// ---------------- LayerNorm: fp32 in (stride 180) -> bf16 out (stride 192, zero pad) -----------
__global__ __launch_bounds__(256) void ln_k(const float* __restrict__ x,
                                            const float* __restrict__ g,
                                            const float* __restrict__ b,
                                            __hip_bfloat16* __restrict__ y) {
    const int wav = threadIdx.x >> 6;
    const int lane = threadIdx.x & 63;
    const int row = blockIdx.x * 4 + wav;
    const float* xr = x + (size_t)row * C;
    float v0 = xr[lane];
    float v1 = xr[lane + 64];
    float v2 = (lane < C - 128) ? xr[lane + 128] : 0.f;
    float sum = v0 + v1 + v2;
    float sq = v0 * v0 + v1 * v1 + v2 * v2;
#pragma unroll
    for (int off = 32; off >= 1; off >>= 1) {
        sum += __shfl_xor(sum, off, 64);
        sq += __shfl_xor(sq, off, 64);
    }
    const float mu = sum * (1.f / C);
    const float var = sq * (1.f / C) - mu * mu;
    const float rstd = rsqrtf(var + 1e-5f);
    __hip_bfloat16* yr = y + (size_t)row * KP1;
#pragma unroll
    for (int e = 0; e < 3; ++e) {
        int col = lane + 64 * e;
        float val = 0.f;
        if (col < C) {
            float vv = (e == 0) ? v0 : (e == 1 ? v1 : v2);
            val = (vv - mu) * rstd * g[col] + b[col];
        }
        yr[col] = __float2bfloat16(val);
    }
}

// ---------------- conv weight pack: OIHW f32 -> bf16 [tap][oc(OCP)][ch(KP)] zero-padded --------
__global__ void wconv_k(const float* __restrict__ w, __hip_bfloat16* __restrict__ wb,
                        int O, int I, int OCP, int KP) {
    int idx = blockIdx.x * 256 + threadIdx.x;
    if (idx >= 9 * OCP * KP) return;
    int tap = idx / (OCP * KP);
    int rem = idx - tap * (OCP * KP);
    int oc = rem / KP, ch = rem - oc * KP;
    float v = (oc < O && ch < I) ? w[((size_t)(oc * I + ch)) * 9 + tap] : 0.f;
    wb[idx] = __float2bfloat16(v);
}

// ---------------- GEMM weight prep: fp32 [K][N] -> bf16 B^T [NP][KPd] zero-padded --------------
__global__ void wprep_k(const float* __restrict__ w, __hip_bfloat16* __restrict__ bt,
                        int K, int N, int KPd, int NP) {
    int idx = blockIdx.x * 256 + threadIdx.x;
    if (idx >= NP * KPd) return;
    int n = idx / KPd, k = idx - n * KPd;
    float v = (n < N && k < K) ? w[(size_t)k * N + n] : 0.f;
    bt[idx] = __float2bfloat16(v);
}

// ---------------- rpb natural-orientation gather: rpbN[h][query][key] bf16 ----------------
__global__ void rpbn_prep_k(const int* __restrict__ rpi, const float* __restrict__ table,
                            __hip_bfloat16* __restrict__ rpbN) {
    int idx = blockIdx.x * 256 + threadIdx.x;  // 65536 = query*256+key
    int t = rpi[idx];
#pragma unroll
    for (int h = 0; h < 6; ++h) rpbN[h * 65536 + idx] = __float2bfloat16(table[t * 6 + h]);
}

// ---------------- MFMA implicit-GEMM conv 3x3, NHWC bf16 in, pad 1 ----------------
template <int CINP, int COUT, int OSTR, int ACT, int OUTBF>
__global__ __launch_bounds__(256) void mconv_k(const __hip_bfloat16* __restrict__ in, int istr,
                                               const __hip_bfloat16* __restrict__ wb,
                                               const float* __restrict__ bias,
                                               void* __restrict__ outp) {
    __shared__ __hip_bfloat16 sP[324 * 40];
    __shared__ __hip_bfloat16 sW[9 * 64 * 40];
    const int tid = threadIdx.x;
    const int tr0 = (blockIdx.x >> 4) * 16, tc0 = (blockIdx.x & 15) * 16;
    const int ocbase = blockIdx.y * 64;
    const int w = tid >> 6, lane = tid & 63, fr = lane & 15, q = lane >> 4;
    constexpr int OCP = ((COUT + 63) / 64) * 64;
    floatx4 acc[4][4] = {};
    for (int c0 = 0; c0 < CINP; c0 += 32) {
        for (int l = tid; l < 324 * 4; l += 256) {
            int pos = l >> 2, part = l & 3;
            int pr = pos / 18, pc = pos - pr * 18;
            int gr = tr0 + pr - 1, gc = tc0 + pc - 1;
            float4 v = make_float4(0.f, 0.f, 0.f, 0.f);
            if (gr >= 0 && gr < 256 && gc >= 0 && gc < 256)
                v = *(const float4*)(in + (size_t)(gr * 256 + gc) * istr + c0 + part * 8);
            *(float4*)(sP + pos * 40 + part * 8) = v;
        }
        for (int l = tid; l < 9 * 64 * 4; l += 256) {
            int part = l & 3, oc = (l >> 2) & 63, tap = l >> 8;
            *(float4*)(sW + tap * 2560 + oc * 40 + part * 8) =
                *(const float4*)(wb + (size_t)(tap * OCP + ocbase + oc) * CINP + c0 + part * 8);
        }
        __syncthreads();
#pragma unroll
        for (int tap = 0; tap < 9; ++tap) {
            const int dy = tap / 3, dx = tap - 3 * (tap / 3);
            bf16x8 af[4], bw[4];
#pragma unroll
            for (int mi = 0; mi < 4; ++mi) {
                int pr = 4 * w + mi + dy, pc = fr + dx;
                af[mi] = *(const bf16x8*)(sP + (pr * 18 + pc) * 40 + q * 8);
            }
#pragma unroll
            for (int nj = 0; nj < 4; ++nj)
                bw[nj] = *(const bf16x8*)(sW + tap * 2560 + (nj * 16 + fr) * 40 + q * 8);
#pragma unroll
            for (int mi = 0; mi < 4; ++mi)
#pragma unroll
                for (int nj = 0; nj < 4; ++nj)
                    acc[mi][nj] =
                        __builtin_amdgcn_mfma_f32_16x16x32_bf16(af[mi], bw[nj], acc[mi][nj], 0, 0, 0);
        }
        __syncthreads();
    }
#pragma unroll
    for (int mi = 0; mi < 4; ++mi) {
#pragma unroll
        for (int r = 0; r < 4; ++r) {
            const int irow = tr0 + 4 * w + mi;
            const int icol = tc0 + q * 4 + r;
            const size_t obase = (size_t)(irow * 256 + icol) * OSTR + ocbase;
#pragma unroll
            for (int nj = 0; nj < 4; ++nj) {
                int oc = ocbase + nj * 16 + fr;
                float bv = (oc < COUT) ? bias[oc] : 0.f;
                float v = acc[mi][nj][r] + bv;
                if (ACT) v = gelu_f(v);
                if (OUTBF) {
                    ((__hip_bfloat16*)outp)[obase + nj * 16 + fr] = __float2bfloat16(v);
                } else {
                    if (oc < COUT) ((float*)outp)[obase + nj * 16 + fr] = v;
                }
            }
        }
    }
}

// ---------------- channel sums ----------------
__global__ __launch_bounds__(192) void chansum_k(const float* __restrict__ y2,
                                                 float* __restrict__ partials) {
    const int tid = threadIdx.x;
    if (tid >= C) return;
    const size_t base = (size_t)blockIdx.x * 256 * C;
    float s = 0.f;
    for (int p = 0; p < 256; ++p) s += y2[base + (size_t)p * C + tid];
    partials[blockIdx.x * C + tid] = s;
}

// ---------------- channel attention MLP (1 block) ----------------
__global__ __launch_bounds__(256) void ca_k(const float* __restrict__ partials,
                                            const float* __restrict__ w1, const float* __restrict__ b1,
                                            const float* __restrict__ w2, const float* __restrict__ b2,
                                            float* __restrict__ scale) {
    __shared__ float mean[C];
    __shared__ float s1[6];
    const int tid = threadIdx.x;
    if (tid < C) {
        float s = 0.f;
        for (int b_ = 0; b_ < 256; ++b_) s += partials[b_ * C + tid];
        mean[tid] = s * (1.f / 65536.f);
    }
    __syncthreads();
    if (tid < 6) {
        float s = b1[tid];
        for (int ch = 0; ch < C; ++ch) s += mean[ch] * w1[tid * C + ch];
        s1[tid] = fmaxf(s, 0.f);
    }
    __syncthreads();
    if (tid < C) {
        float s = b2[tid];
#pragma unroll
        for (int j = 0; j < 6; ++j) s += s1[j] * w2[tid * 6 + j];
        scale[tid] = 1.f / (1.f + __expf(-s));
    }
}

// ---------------- bf16 MFMA GEMM: BM=128, BN in {64,128}, BK=32, 4 waves (2x2) ----------
template <int MODE, int BN>
__global__ __launch_bounds__(256) void mgemm_k(const unsigned short* __restrict__ A,
                                               const unsigned short* __restrict__ BT,
                                               const float* __restrict__ bias,
                                               const float* __restrict__ xres,
                                               const float* __restrict__ scale,
                                               void* __restrict__ Cout,
                                               int KPd, int N, int cstride, int rowoff) {
    __shared__ unsigned short As[128 * 40];
    __shared__ unsigned short Bs[BN * 40];
    constexpr int NJ = BN / 32;
    const int tid = threadIdx.x;
    const int m0 = blockIdx.y * 128, n0 = blockIdx.x * BN;
    const int arow_l = tid >> 1;
    const int akofs = (tid & 1) * 16;
    size_t arow;
    if (MODE == 3)
        arow = (size_t)win2pix(rowoff + m0 + arow_l) * KPd;
    else
        arow = (size_t)(m0 + arow_l) * KPd;
    const int brow_l = (BN == 128) ? (tid >> 1) : (tid >> 2);
    const int bkofs = (BN == 128) ? ((tid & 1) * 16) : ((tid & 3) * 8);
    const size_t brow = (size_t)(n0 + brow_l) * KPd;
    const int wave = tid >> 6, lane = tid & 63;
    const int wm = (wave & 1) * 64, wn = (wave >> 1) * (BN / 2);
    const int fr = lane & 15, q = lane >> 4;
    floatx4 acc[4][NJ] = {};
    for (int k0 = 0; k0 < KPd; k0 += 32) {
        *(float4*)(&As[arow_l * 40 + akofs]) = *(const float4*)(A + arow + k0 + akofs);
        *(float4*)(&As[arow_l * 40 + akofs + 8]) = *(const float4*)(A + arow + k0 + akofs + 8);
        if (BN == 128) {
            *(float4*)(&Bs[brow_l * 40 + bkofs]) = *(const float4*)(BT + brow + k0 + bkofs);
            *(float4*)(&Bs[brow_l * 40 + bkofs + 8]) = *(const float4*)(BT + brow + k0 + bkofs + 8);
        } else {
            *(float4*)(&Bs[brow_l * 40 + bkofs]) = *(const float4*)(BT + brow + k0 + bkofs);
        }
        __syncthreads();
        bf16x8 af[4], fB[NJ];
#pragma unroll
        for (int i = 0; i < 4; ++i)
            af[i] = *(const bf16x8*)(&As[(wm + i * 16 + fr) * 40 + q * 8]);
#pragma unroll
        for (int j = 0; j < NJ; ++j)
            fB[j] = *(const bf16x8*)(&Bs[(wn + j * 16 + fr) * 40 + q * 8]);
#pragma unroll
        for (int i = 0; i < 4; ++i)
#pragma unroll
            for (int j = 0; j < NJ; ++j)
                acc[i][j] = __builtin_amdgcn_mfma_f32_16x16x32_bf16(af[i], fB[j], acc[i][j], 0, 0, 0);
        __syncthreads();
    }
#pragma unroll
    for (int i = 0; i < 4; ++i) {
#pragma unroll
        for (int r = 0; r < 4; ++r) {
            const int grow = m0 + wm + i * 16 + q * 4 + r;
            int pix = 0;
            if (MODE == 4) pix = win2pix(rowoff + grow);
#pragma unroll
            for (int j = 0; j < NJ; ++j) {
                const int col = n0 + wn + j * 16 + fr;
                float v = acc[i][j][r];
                if (MODE == 1 || MODE == 3) {
                    if (col < cstride) {
                        float vv = 0.f;
                        if (col < N) {
                            vv = v + bias[col];
                            if (MODE == 1) vv = gelu_f(vv);
                        }
                        ((__hip_bfloat16*)Cout)[(size_t)grow * cstride + col] = __float2bfloat16(vv);
                    }
                } else if (MODE == 2) {
                    if (col < N) {
                        float* o = (float*)Cout;
                        size_t ix = (size_t)grow * cstride + col;
                        o[ix] = v + bias[col] + xres[ix];
                    }
                } else if (MODE == 4) {
                    if (col < N) {
                        float* o = (float*)Cout;
                        size_t ix = (size_t)pix * 180 + col;
                        o[ix] = xres[ix] + v + bias[col] + o[ix] * scale[col] * 0.01f;
                    }
                }
            }
        }
    }
}

// ---------------- MFMA flash attention v5: S^T + shfl-based P->A conversion ------
// block per (window, head), 4 waves x 64 q-rows. No P LDS buffer (cross-lane shfl instead).
// S^T = mfma(kf, qf): lane holds (query=fr, keys=q*4+r) -> A-frag built with 8 shfls/(kc,mi).
// kk stride 40 (conflict-free b128), LDS = 37,376 B.
__global__ __launch_bounds__(256, 3) void attn5_k(const __hip_bfloat16* __restrict__ qkv,  // [R][576]
                                                  const __hip_bfloat16* __restrict__ rpbN, // [h][qry][key]
                                                  const float* __restrict__ mask,          // [wig][qry][key]
                                                  __hip_bfloat16* __restrict__ attn_out,   // [R][192]
                                                  int wbase) {
    const int wl = blockIdx.x, h = blockIdx.y;
    const int wig = wbase + wl;
    const bool edge = ((wig >> 4) == 15) || ((wig & 15) == 15);
    const int tid = threadIdx.x;
    const int w = tid >> 6, lane = tid & 63;
    const int fr = lane & 15, q = lane >> 4;
    __shared__ __hip_bfloat16 kk[256 * 40];   // [key][d pad40]
    __shared__ __hip_bfloat16 vT[32 * 264];   // [d][key pad264]

    union UB2 { unsigned int u; __hip_bfloat162 h2; };
    for (int l = tid; l < 256 * 15; l += 256) {
        int key = l / 15, dw_ = l - key * 15;
        const unsigned int* ks =
            (const unsigned int*)(qkv + (size_t)(wl * 256 + key) * 576 + 180 + h * 30);
        *(unsigned int*)(kk + key * 40 + dw_ * 2) = ks[dw_];
        UB2 vv; vv.u = ks[90 + dw_];
        vT[(2 * dw_) * 264 + key] = vv.h2.x;
        vT[(2 * dw_ + 1) * 264 + key] = vv.h2.y;
    }
    *(unsigned int*)(kk + tid * 40 + 30) = 0u;  // zero d=30,31 (K-dim pad)
    __syncthreads();

    // Q B-fragments (raw; scale folded into bias FMA). Garbage at d=30,31 annihilated by kk zeros.
    const int rowbase = wl * 256 + w * 64;
    union U8 { unsigned int u[4]; bf16x8 v; };
    bf16x8 qf[4];
#pragma unroll
    for (int qi = 0; qi < 4; ++qi) {
        const unsigned int* p32 =
            (const unsigned int*)(qkv + (size_t)(rowbase + qi * 16 + fr) * 576 + h * 30);
        U8 t;
#pragma unroll
        for (int jj = 0; jj < 4; ++jj) t.u[jj] = p32[q * 4 + jj];
        qf[qi] = t.v;
    }

    const float SC = 0.18257418583505536f;
    float lsum[4] = {};
    floatx4 o_[4][2] = {};
    const __hip_bfloat16* rpbh = rpbN + (size_t)h * 65536;
    const float* maskw = mask + (size_t)wig * 65536;
    const int srcA = fr + ((q & 1) << 5);  // lane fr + 2(q&1)*16
    const int srcB = srcA + 16;

    for (int nc = 0; nc < 4; ++nc) {
        bf16x8 kf[4];
#pragma unroll
        for (int ki = 0; ki < 4; ++ki)
            kf[ki] = *(const bf16x8*)(kk + (nc * 64 + ki * 16 + fr) * 40 + q * 8);
        unsigned int dw[4][4][2];  // [ki][qi][dword]: packed bf16 P values
#pragma unroll
        for (int qi = 0; qi < 4; ++qi) {
            floatx4 s_[4] = {};
#pragma unroll
            for (int ki = 0; ki < 4; ++ki)
                s_[ki] = __builtin_amdgcn_mfma_f32_16x16x32_bf16(kf[ki], qf[qi], s_[ki], 0, 0, 0);
            const size_t qoff = ((size_t)(w * 64 + qi * 16 + fr)) * 256 + nc * 64 + q * 4;
#pragma unroll
            for (int ki = 0; ki < 4; ++ki) {
                uint2 rb = *(const uint2*)(rpbh + qoff + ki * 16);
                float b0 = bflo(rb.x), b1 = bfhi(rb.x), b2 = bflo(rb.y), b3 = bfhi(rb.y);
                if (edge) {
                    float4 mv = *(const float4*)(maskw + qoff + ki * 16);
                    b0 += mv.x; b1 += mv.y; b2 += mv.z; b3 += mv.w;
                }
                float p0 = __expf(fmaf(s_[ki][0], SC, b0));
                float p1 = __expf(fmaf(s_[ki][1], SC, b1));
                float p2 = __expf(fmaf(s_[ki][2], SC, b2));
                float p3 = __expf(fmaf(s_[ki][3], SC, b3));
                lsum[qi] += (p0 + p1) + (p2 + p3);
                __hip_bfloat162 lo = {__float2bfloat16(p0), __float2bfloat16(p1)};
                __hip_bfloat162 hi = {__float2bfloat16(p2), __float2bfloat16(p3)};
                UB2 ul, uh; ul.h2 = lo; uh.h2 = hi;
                dw[ki][qi][0] = ul.u;
                dw[ki][qi][1] = uh.u;
            }
        }
        // PV in two 32-key halves; A-frag built via cross-lane shfl (no LDS round-trip)
#pragma unroll
        for (int kc = 0; kc < 2; ++kc) {
            bf16x8 pa[4];
#pragma unroll
            for (int mi = 0; mi < 4; ++mi) {
                unsigned g0 = __shfl((int)dw[2 * kc][mi][0], srcA, 64);
                unsigned g1 = __shfl((int)dw[2 * kc][mi][1], srcA, 64);
                unsigned g2 = __shfl((int)dw[2 * kc][mi][0], srcB, 64);
                unsigned g3 = __shfl((int)dw[2 * kc][mi][1], srcB, 64);
                unsigned h0 = __shfl((int)dw[2 * kc + 1][mi][0], srcA, 64);
                unsigned h1 = __shfl((int)dw[2 * kc + 1][mi][1], srcA, 64);
                unsigned h2 = __shfl((int)dw[2 * kc + 1][mi][0], srcB, 64);
                unsigned h3 = __shfl((int)dw[2 * kc + 1][mi][1], srcB, 64);
                U8 t;
                const bool lo = (q < 2);
                t.u[0] = lo ? g0 : h0;
                t.u[1] = lo ? g1 : h1;
                t.u[2] = lo ? g2 : h2;
                t.u[3] = lo ? g3 : h3;
                pa[mi] = t.v;
            }
            bf16x8 vb[2];
#pragma unroll
            for (int dj = 0; dj < 2; ++dj)
                vb[dj] = *(const bf16x8*)(vT + (dj * 16 + fr) * 264 + nc * 64 + kc * 32 + q * 8);
#pragma unroll
            for (int mi = 0; mi < 4; ++mi)
#pragma unroll
                for (int dj = 0; dj < 2; ++dj)
                    o_[mi][dj] =
                        __builtin_amdgcn_mfma_f32_16x16x32_bf16(pa[mi], vb[dj], o_[mi][dj], 0, 0, 0);
        }
    }
    // row sums: reduce across q-groups, redistribute via shfl (query = q*4+r lane)
#pragma unroll
    for (int qi = 0; qi < 4; ++qi) {
        lsum[qi] += __shfl_xor(lsum[qi], 16, 64);
        lsum[qi] += __shfl_xor(lsum[qi], 32, 64);
    }
#pragma unroll
    for (int mi = 0; mi < 4; ++mi) {
#pragma unroll
        for (int r = 0; r < 4; ++r) {
            float tot = __shfl(lsum[mi], q * 4 + r, 64);
            float inv = 1.f / tot;
            const int row_local = rowbase + mi * 16 + q * 4 + r;
            __hip_bfloat16* orow = attn_out + (size_t)row_local * KP1 + h * 30;
#pragma unroll
            for (int dj = 0; dj < 2; ++dj) {
                int d = dj * 16 + fr;
                if (d < 30) orow[d] = __float2bfloat16(o_[mi][dj][r] * inv);
            }
        }
    }
    if (h == 0) {
        for (int l = tid; l < 256 * 12; l += 256) {
            int rr2 = l / 12, d = l - rr2 * 12;
            attn_out[(size_t)(wl * 256 + rr2) * KP1 + 180 + d] = __float2bfloat16(0.f);
        }
    }
}

extern "C" void kernel_launch(void* const* d_in, const int* in_sizes, int n_in, void* d_out,
                              int out_size, void* d_ws, size_t ws_size, hipStream_t stream) {
    (void)in_sizes; (void)n_in; (void)out_size; (void)ws_size;
    const float* x = (const float*)d_in[0];
    const int* rpi = (const int*)d_in[3];
    const float* mask = (const float*)d_in[4];
    const float* n1g = (const float*)d_in[5];
    const float* n1b = (const float*)d_in[6];
    const float* qkvw = (const float*)d_in[7];
    const float* qkvb = (const float*)d_in[8];
    const float* rpbt = (const float*)d_in[9];
    const float* projw = (const float*)d_in[10];
    const float* projb = (const float*)d_in[11];
    const float* c1w = (const float*)d_in[12];
    const float* c1b = (const float*)d_in[13];
    const float* c2w = (const float*)d_in[14];
    const float* c2b = (const float*)d_in[15];
    const float* ca1w = (const float*)d_in[16];
    const float* ca1b = (const float*)d_in[17];
    const float* ca2w = (const float*)d_in[18];
    const float* ca2b = (const float*)d_in[19];
    const float* n2g = (const float*)d_in[20];
    const float* n2b = (const float*)d_in[21];
    const float* f1w = (const float*)d_in[22];
    const float* f1b = (const float*)d_in[23];
    const float* f2w = (const float*)d_in[24];
    const float* f2b = (const float*)d_in[25];

    float* ws = (float*)d_ws;
    float* out = (float*)d_out;  // y2 -> x2 -> final output (in place, disjoint phases)

    // workspace layout (floats; offsets 16B-aligned). ~77.8 MB total.
    float* xn_f     = ws;                    // 6,291,456 (65536x192 bf16)
    float* bufC     = xn_f + 6291456;        // 12,582,912 (y1b | qkvC+attnC | h1, all bf16)
    float* partials = bufC + 12582912;       // 46,080
    float* scalep   = partials + 46080;      // 192
    float* rpbN_f   = scalep + 192;          // 196,608 (6x65536 bf16)
    float* wb1_f    = rpbN_f + 196608;       // 55,296
    float* wb2_f    = wb1_f + 55296;         // 55,296
    float* qkvbt_f  = wb2_f + 55296;         // 61,440  (640x192 bf16)
    float* projbt_f = qkvbt_f + 61440;       // 18,432  (192x192 bf16)
    float* f1bt_f   = projbt_f + 18432;      // 73,728  (768x192 bf16)
    float* f2bt_f   = f1bt_f + 73728;        // 73,728  (192x768 bf16)

    __hip_bfloat16* xn    = (__hip_bfloat16*)xn_f;
    __hip_bfloat16* y1b   = (__hip_bfloat16*)bufC;                  // 65536x64
    __hip_bfloat16* qkvC  = (__hip_bfloat16*)bufC;                  // 32768x576
    __hip_bfloat16* attnC = (__hip_bfloat16*)(bufC + 9437184);      // 32768x192
    __hip_bfloat16* h1    = (__hip_bfloat16*)bufC;                  // 32768x768
    __hip_bfloat16* rpbN   = (__hip_bfloat16*)rpbN_f;
    __hip_bfloat16* wb1    = (__hip_bfloat16*)wb1_f;
    __hip_bfloat16* wb2    = (__hip_bfloat16*)wb2_f;
    __hip_bfloat16* qkvbt  = (__hip_bfloat16*)qkvbt_f;
    __hip_bfloat16* projbt = (__hip_bfloat16*)projbt_f;
    __hip_bfloat16* f1bt   = (__hip_bfloat16*)f1bt_f;
    __hip_bfloat16* f2bt   = (__hip_bfloat16*)f2bt_f;

    // ---- prep ----
    rpbn_prep_k<<<256, 256, 0, stream>>>(rpi, rpbt, rpbN);
    wconv_k<<<(9 * 64 * 192 + 255) / 256, 256, 0, stream>>>(c1w, wb1, 60, 180, 64, 192);
    wconv_k<<<(9 * 192 * 64 + 255) / 256, 256, 0, stream>>>(c2w, wb2, 180, 60, 192, 64);
    wprep_k<<<(640 * 192 + 255) / 256, 256, 0, stream>>>(qkvw, qkvbt, 180, 540, 192, 640);
    wprep_k<<<(192 * 192 + 255) / 256, 256, 0, stream>>>(projw, projbt, 180, 180, 192, 192);
    wprep_k<<<(768 * 192 + 255) / 256, 256, 0, stream>>>(f1w, f1bt, 180, 720, 192, 768);
    wprep_k<<<(192 * 768 + 255) / 256, 256, 0, stream>>>(f2w, f2bt, 720, 180, 768, 192);

    // ---- LN1 -> bf16 ----
    ln_k<<<NTOK / 4, 256, 0, stream>>>(x, n1g, n1b, xn);

    // ---- CAB conv branch (MFMA): y2 lives in d_out ----
    mconv_k<192, 60, 64, 1, 1><<<dim3(256, 1), 256, 0, stream>>>(xn, 192, wb1, c1b, y1b);
    mconv_k<64, 180, 180, 0, 0><<<dim3(256, 3), 256, 0, stream>>>(y1b, 64, wb2, c2b, out);
    chansum_k<<<256, 192, 0, stream>>>(out, partials);
    ca_k<<<1, 256, 0, stream>>>(partials, ca1w, ca1b, ca2w, ca2b, scalep);

    // ---- attention branch, 2 chunks of 128 windows; proj epilogue fuses the merge ----
    for (int ck = 0; ck < 2; ++ck) {
        const int rowoff = ck * RCHUNK;
        mgemm_k<3, 128><<<dim3(5, RCHUNK / 128), 256, 0, stream>>>(
            (const unsigned short*)xn, (const unsigned short*)qkvbt, qkvb, nullptr, nullptr,
            qkvC, 192, 540, 576, rowoff);
        attn5_k<<<dim3(128, 6), 256, 0, stream>>>(qkvC, rpbN, mask, attnC, ck * 128);
        mgemm_k<4, 64><<<dim3(3, RCHUNK / 128), 256, 0, stream>>>(
            (const unsigned short*)attnC, (const unsigned short*)projbt, projb, x, scalep,
            out, 192, 180, 180, rowoff);
    }

    // ---- LN2 (x2 in d_out) -> bf16 xm ----
    ln_k<<<NTOK / 4, 256, 0, stream>>>(out, n2g, n2b, xn);

    // ---- MLP, 2 chunks; fc2 adds residual and overwrites d_out in place ----
    for (int ck = 0; ck < 2; ++ck) {
        const int rowoff = ck * RCHUNK;
        mgemm_k<1, 128><<<dim3(6, RCHUNK / 128), 256, 0, stream>>>(
            (const unsigned short*)(xn + (size_t)rowoff * KP1), (const unsigned short*)f1bt,
            f1b, nullptr, nullptr, h1, 192, 720, 768, 0);
        mgemm_k<2, 64><<<dim3(3, RCHUNK / 128), 256, 0, stream>>>(
            (const unsigned short*)h1, (const unsigned short*)f2bt, f2b,
            out + (size_t)rowoff * 180, nullptr, out + (size_t)rowoff * 180, 768, 180, 180, 0);
    }
}

// Round 9
// 807.941 us; speedup vs baseline: 4.9681x; 1.0330x over previous
//
#include <hip/hip_runtime.h>
#include <hip/hip_bf16.h>
#include <math.h>

#define NTOK 65536
#define C 180
#define KP1 192      // padded K for C=180
#define RCHUNK 32768 // rows per chunk (128 windows)

typedef __attribute__((ext_vector_type(8))) __bf16 bf16x8;
typedef __attribute__((ext_vector_type(4))) float floatx4;

__device__ __forceinline__ float gelu_f(float v) {
    return 0.5f * v * (1.f + erff(v * 0.7071067811865475f));
}
__device__ __forceinline__ float bflo(unsigned int u) { return __uint_as_float(u << 16); }
__device__ __forceinline__ float bfhi(unsigned int u) { return __uint_as_float(u & 0xffff0000u); }

// window-row (shifted-window order) -> pixel row index in [0, 65536)
__device__ __forceinline__ int win2pix(int wrow) {
    int wi = wrow >> 8, ni = wrow & 255;
    int r2 = ((wi >> 4) << 4) | (ni >> 4);
    int c2 = ((wi & 15) << 4) | (ni & 15);
    int r = (r2 + 8) & 255, c = (c2 + 8) & 255;
    return (r << 8) | c;
}

// ---------------- LayerNorm: fp32 in (stride 180) -> bf16 out (stride 192, zero pad) -----------
__global__ __launch_bounds__(256) void ln_k(const float* __restrict__ x,
                                            const float* __restrict__ g,
                                            const float* __restrict__ b,
                                            __hip_bfloat16* __restrict__ y) {
    const int wav = threadIdx.x >> 6;
    const int lane = threadIdx.x & 63;
    const int row = blockIdx.x * 4 + wav;
    const float* xr = x + (size_t)row * C;
    float v0 = xr[lane];
    float v1 = xr[lane + 64];
    float v2 = (lane < C - 128) ? xr[lane + 128] : 0.f;
    float sum = v0 + v1 + v2;
    float sq = v0 * v0 + v1 * v1 + v2 * v2;
#pragma unroll
    for (int off = 32; off >= 1; off >>= 1) {
        sum += __shfl_xor(sum, off, 64);
        sq += __shfl_xor(sq, off, 64);
    }
    const float mu = sum * (1.f / C);
    const float var = sq * (1.f / C) - mu * mu;
    const float rstd = rsqrtf(var + 1e-5f);
    __hip_bfloat16* yr = y + (size_t)row * KP1;
#pragma unroll
    for (int e = 0; e < 3; ++e) {
        int col = lane + 64 * e;
        float val = 0.f;
        if (col < C) {
            float vv = (e == 0) ? v0 : (e == 1 ? v1 : v2);
            val = (vv - mu) * rstd * g[col] + b[col];
        }
        yr[col] = __float2bfloat16(val);
    }
}

// ---------------- fused weight/bias prep (one dispatch) ----------------
__device__ __forceinline__ void wconv_item(const float* __restrict__ w,
                                           __hip_bfloat16* __restrict__ wb,
                                           int O, int I, int OCP, int KP, int idx) {
    int tap = idx / (OCP * KP);
    int rem = idx - tap * (OCP * KP);
    int oc = rem / KP, ch = rem - oc * KP;
    float v = (oc < O && ch < I) ? w[((size_t)(oc * I + ch)) * 9 + tap] : 0.f;
    wb[idx] = __float2bfloat16(v);
}
__device__ __forceinline__ void wprep_item(const float* __restrict__ w,
                                           __hip_bfloat16* __restrict__ bt,
                                           int K, int N, int KPd, int idx) {
    int n = idx / KPd, k = idx - n * KPd;
    float v = (n < N && k < K) ? w[(size_t)k * N + n] : 0.f;
    bt[idx] = __float2bfloat16(v);
}
// ranges: [0,65536) rpbN | +110592 wconv1 | +110592 wconv2 | +122880 qkv | +36864 proj |
//         +147456 f1 | +147456 f2   total 741,376
__global__ void prep_all_k(const int* __restrict__ rpi, const float* __restrict__ table,
                           __hip_bfloat16* __restrict__ rpbN,
                           const float* __restrict__ c1w, __hip_bfloat16* __restrict__ wb1,
                           const float* __restrict__ c2w, __hip_bfloat16* __restrict__ wb2,
                           const float* __restrict__ qkvw, __hip_bfloat16* __restrict__ qkvbt,
                           const float* __restrict__ projw, __hip_bfloat16* __restrict__ projbt,
                           const float* __restrict__ f1w, __hip_bfloat16* __restrict__ f1bt,
                           const float* __restrict__ f2w, __hip_bfloat16* __restrict__ f2bt) {
    int idx = blockIdx.x * 256 + threadIdx.x;
    if (idx < 65536) {
        int t = rpi[idx];
#pragma unroll
        for (int h = 0; h < 6; ++h) rpbN[h * 65536 + idx] = __float2bfloat16(table[t * 6 + h]);
        return;
    }
    idx -= 65536;
    if (idx < 110592) { wconv_item(c1w, wb1, 60, 180, 64, 192, idx); return; }
    idx -= 110592;
    if (idx < 110592) { wconv_item(c2w, wb2, 180, 60, 192, 64, idx); return; }
    idx -= 110592;
    if (idx < 122880) { wprep_item(qkvw, qkvbt, 180, 540, 192, idx); return; }
    idx -= 122880;
    if (idx < 36864) { wprep_item(projw, projbt, 180, 180, 192, idx); return; }
    idx -= 36864;
    if (idx < 147456) { wprep_item(f1w, f1bt, 180, 720, 192, idx); return; }
    idx -= 147456;
    if (idx < 147456) { wprep_item(f2w, f2bt, 720, 180, 768, idx); return; }
}

// ---------------- MFMA implicit-GEMM conv 3x3, NHWC bf16 in, pad 1 ----------------
// tile = TH x 16 pixels, 64 oc; waves cover TH/4 pixel rows each
template <int TH, int CINP, int COUT, int OSTR, int ACT, int OUTBF>
__global__ __launch_bounds__(256) void mconv_k(const __hip_bfloat16* __restrict__ in, int istr,
                                               const __hip_bfloat16* __restrict__ wb,
                                               const float* __restrict__ bias,
                                               void* __restrict__ outp) {
    constexpr int MI = TH / 4;
    __shared__ __hip_bfloat16 sP[(TH + 2) * 18 * 40];
    __shared__ __hip_bfloat16 sW[9 * 64 * 40];
    const int tid = threadIdx.x;
    const int tr0 = (blockIdx.x >> 4) * TH, tc0 = (blockIdx.x & 15) * 16;
    const int ocbase = blockIdx.y * 64;
    const int w = tid >> 6, lane = tid & 63, fr = lane & 15, q = lane >> 4;
    constexpr int OCP = ((COUT + 63) / 64) * 64;
    floatx4 acc[MI][4] = {};
    for (int c0 = 0; c0 < CINP; c0 += 32) {
        for (int l = tid; l < (TH + 2) * 18 * 4; l += 256) {
            int pos = l >> 2, part = l & 3;
            int pr = pos / 18, pc = pos - pr * 18;
            int gr = tr0 + pr - 1, gc = tc0 + pc - 1;
            float4 v = make_float4(0.f, 0.f, 0.f, 0.f);
            if (gr >= 0 && gr < 256 && gc >= 0 && gc < 256)
                v = *(const float4*)(in + (size_t)(gr * 256 + gc) * istr + c0 + part * 8);
            *(float4*)(sP + pos * 40 + part * 8) = v;
        }
        for (int l = tid; l < 9 * 64 * 4; l += 256) {
            int part = l & 3, oc = (l >> 2) & 63, tap = l >> 8;
            *(float4*)(sW + tap * 2560 + oc * 40 + part * 8) =
                *(const float4*)(wb + (size_t)(tap * OCP + ocbase + oc) * CINP + c0 + part * 8);
        }
        __syncthreads();
#pragma unroll
        for (int tap = 0; tap < 9; ++tap) {
            const int dy = tap / 3, dx = tap - 3 * (tap / 3);
            bf16x8 af[MI], bw[4];
#pragma unroll
            for (int mi = 0; mi < MI; ++mi) {
                int pr = MI * w + mi + dy, pc = fr + dx;
                af[mi] = *(const bf16x8*)(sP + (pr * 18 + pc) * 40 + q * 8);
            }
#pragma unroll
            for (int nj = 0; nj < 4; ++nj)
                bw[nj] = *(const bf16x8*)(sW + tap * 2560 + (nj * 16 + fr) * 40 + q * 8);
#pragma unroll
            for (int mi = 0; mi < MI; ++mi)
#pragma unroll
                for (int nj = 0; nj < 4; ++nj)
                    acc[mi][nj] =
                        __builtin_amdgcn_mfma_f32_16x16x32_bf16(af[mi], bw[nj], acc[mi][nj], 0, 0, 0);
        }
        __syncthreads();
    }
#pragma unroll
    for (int mi = 0; mi < MI; ++mi) {
#pragma unroll
        for (int r = 0; r < 4; ++r) {
            const int irow = tr0 + MI * w + mi;
            const int icol = tc0 + q * 4 + r;
            const size_t obase = (size_t)(irow * 256 + icol) * OSTR + ocbase;
#pragma unroll
            for (int nj = 0; nj < 4; ++nj) {
                int oc = ocbase + nj * 16 + fr;
                float bv = (oc < COUT) ? bias[oc] : 0.f;
                float v = acc[mi][nj][r] + bv;
                if (ACT) v = gelu_f(v);
                if (OUTBF) {
                    ((__hip_bfloat16*)outp)[obase + nj * 16 + fr] = __float2bfloat16(v);
                } else {
                    if (oc < COUT) ((float*)outp)[obase + nj * 16 + fr] = v;
                }
            }
        }
    }
}

// ---------------- channel sums ----------------
__global__ __launch_bounds__(192) void chansum_k(const float* __restrict__ y2,
                                                 float* __restrict__ partials) {
    const int tid = threadIdx.x;
    if (tid >= C) return;
    const size_t base = (size_t)blockIdx.x * 256 * C;
    float s = 0.f;
    for (int p = 0; p < 256; ++p) s += y2[base + (size_t)p * C + tid];
    partials[blockIdx.x * C + tid] = s;
}

// ---------------- channel attention MLP (1 block) ----------------
__global__ __launch_bounds__(256) void ca_k(const float* __restrict__ partials,
                                            const float* __restrict__ w1, const float* __restrict__ b1,
                                            const float* __restrict__ w2, const float* __restrict__ b2,
                                            float* __restrict__ scale) {
    __shared__ float mean[C];
    __shared__ float s1[6];
    const int tid = threadIdx.x;
    if (tid < C) {
        float s = 0.f;
        for (int b_ = 0; b_ < 256; ++b_) s += partials[b_ * C + tid];
        mean[tid] = s * (1.f / 65536.f);
    }
    __syncthreads();
    if (tid < 6) {
        float s = b1[tid];
        for (int ch = 0; ch < C; ++ch) s += mean[ch] * w1[tid * C + ch];
        s1[tid] = fmaxf(s, 0.f);
    }
    __syncthreads();
    if (tid < C) {
        float s = b2[tid];
#pragma unroll
        for (int j = 0; j < 6; ++j) s += s1[j] * w2[tid * 6 + j];
        scale[tid] = 1.f / (1.f + __expf(-s));
    }
}

// ---------------- bf16 MFMA GEMM: BM=128, BN in {64,128}, BK=32, 4 waves (2x2) ----------
// MODE 1 fc1: bf16 = gelu(A*B+bias)   MODE 2 fc2: f32 = A*B+bias+xres
// MODE 3 qkv: A rows via win2pix; bf16 out
// MODE 5 proj: A planar [h][R][32] (R in cstride); f32 merge at win2pix rows
template <int MODE, int BN>
__global__ __launch_bounds__(256) void mgemm_k(const unsigned short* __restrict__ A,
                                               const unsigned short* __restrict__ BT,
                                               const float* __restrict__ bias,
                                               const float* __restrict__ xres,
                                               const float* __restrict__ scale,
                                               void* __restrict__ Cout,
                                               int KPd, int N, int cstride, int rowoff) {
    __shared__ unsigned short As[128 * 40];
    __shared__ unsigned short Bs[BN * 40];
    constexpr int NJ = BN / 32;
    const int tid = threadIdx.x;
    const int m0 = blockIdx.y * 128, n0 = blockIdx.x * BN;
    const int arow_l = tid >> 1;
    const int akofs = (tid & 1) * 16;
    size_t arow;
    if (MODE == 3)
        arow = (size_t)win2pix(rowoff + m0 + arow_l) * KPd;
    else
        arow = (size_t)(m0 + arow_l) * KPd;
    const int brow_l = (BN == 128) ? (tid >> 1) : (tid >> 2);
    const int bkofs = (BN == 128) ? ((tid & 1) * 16) : ((tid & 3) * 8);
    const size_t brow = (size_t)(n0 + brow_l) * KPd;
    const int wave = tid >> 6, lane = tid & 63;
    const int wm = (wave & 1) * 64, wn = (wave >> 1) * (BN / 2);
    const int fr = lane & 15, q = lane >> 4;
    floatx4 acc[4][NJ] = {};
    for (int k0 = 0; k0 < KPd; k0 += 32) {
        if (MODE == 5) {
            const unsigned short* Ap = A + ((size_t)(k0 >> 5) * cstride + (m0 + arow_l)) * 32;
            *(float4*)(&As[arow_l * 40 + akofs]) = *(const float4*)(Ap + akofs);
            *(float4*)(&As[arow_l * 40 + akofs + 8]) = *(const float4*)(Ap + akofs + 8);
        } else {
            *(float4*)(&As[arow_l * 40 + akofs]) = *(const float4*)(A + arow + k0 + akofs);
            *(float4*)(&As[arow_l * 40 + akofs + 8]) = *(const float4*)(A + arow + k0 + akofs + 8);
        }
        if (BN == 128) {
            *(float4*)(&Bs[brow_l * 40 + bkofs]) = *(const float4*)(BT + brow + k0 + bkofs);
            *(float4*)(&Bs[brow_l * 40 + bkofs + 8]) = *(const float4*)(BT + brow + k0 + bkofs + 8);
        } else {
            *(float4*)(&Bs[brow_l * 40 + bkofs]) = *(const float4*)(BT + brow + k0 + bkofs);
        }
        __syncthreads();
        bf16x8 af[4], fB[NJ];
#pragma unroll
        for (int i = 0; i < 4; ++i)
            af[i] = *(const bf16x8*)(&As[(wm + i * 16 + fr) * 40 + q * 8]);
#pragma unroll
        for (int j = 0; j < NJ; ++j)
            fB[j] = *(const bf16x8*)(&Bs[(wn + j * 16 + fr) * 40 + q * 8]);
#pragma unroll
        for (int i = 0; i < 4; ++i)
#pragma unroll
            for (int j = 0; j < NJ; ++j)
                acc[i][j] = __builtin_amdgcn_mfma_f32_16x16x32_bf16(af[i], fB[j], acc[i][j], 0, 0, 0);
        __syncthreads();
    }
#pragma unroll
    for (int i = 0; i < 4; ++i) {
#pragma unroll
        for (int r = 0; r < 4; ++r) {
            const int grow = m0 + wm + i * 16 + q * 4 + r;
            int pix = 0;
            if (MODE == 5) pix = win2pix(rowoff + grow);
#pragma unroll
            for (int j = 0; j < NJ; ++j) {
                const int col = n0 + wn + j * 16 + fr;
                float v = acc[i][j][r];
                if (MODE == 1 || MODE == 3) {
                    if (col < cstride) {
                        float vv = 0.f;
                        if (col < N) {
                            vv = v + bias[col];
                            if (MODE == 1) vv = gelu_f(vv);
                        }
                        ((__hip_bfloat16*)Cout)[(size_t)grow * cstride + col] = __float2bfloat16(vv);
                    }
                } else if (MODE == 2) {
                    if (col < N) {
                        float* o = (float*)Cout;
                        size_t ix = (size_t)grow * 180 + col;
                        o[ix] = v + bias[col] + xres[ix];
                    }
                } else if (MODE == 5) {
                    if (col < N) {
                        float* o = (float*)Cout;
                        size_t ix = (size_t)pix * 180 + col;
                        o[ix] = xres[ix] + v + bias[col] + o[ix] * scale[col] * 0.01f;
                    }
                }
            }
        }
    }
}

// ---------------- MFMA flash attention v6: S^T + shfl P->A, planar coalesced output ------
// block per (window, head); output plane attn_out[h][RCHUNK][32] (contiguous per block)
__global__ __launch_bounds__(256, 3) void attn6_k(const __hip_bfloat16* __restrict__ qkv,  // [R][576]
                                                  const __hip_bfloat16* __restrict__ rpbN, // [h][qry][key]
                                                  const float* __restrict__ mask,          // [wig][qry][key]
                                                  __hip_bfloat16* __restrict__ attn_out,   // [6][R][32]
                                                  int wbase) {
    const int wl = blockIdx.x, h = blockIdx.y;
    const int wig = wbase + wl;
    const bool edge = ((wig >> 4) == 15) || ((wig & 15) == 15);
    const int tid = threadIdx.x;
    const int w = tid >> 6, lane = tid & 63;
    const int fr = lane & 15, q = lane >> 4;
    __shared__ __hip_bfloat16 kk[256 * 40];   // [key][d pad40]
    __shared__ __hip_bfloat16 vT[32 * 264];   // [d][key pad264]

    union UB2 { unsigned int u; __hip_bfloat162 h2; };
    for (int l = tid; l < 256 * 15; l += 256) {
        int key = l / 15, dw_ = l - key * 15;
        const unsigned int* ks =
            (const unsigned int*)(qkv + (size_t)(wl * 256 + key) * 576 + 180 + h * 30);
        *(unsigned int*)(kk + key * 40 + dw_ * 2) = ks[dw_];
        UB2 vv; vv.u = ks[90 + dw_];
        vT[(2 * dw_) * 264 + key] = vv.h2.x;
        vT[(2 * dw_ + 1) * 264 + key] = vv.h2.y;
    }
    *(unsigned int*)(kk + tid * 40 + 30) = 0u;  // zero d=30,31 (K-dim pad)
    // zero vT rows 30,31 (PV dj=1 cols 30,31 would otherwise read garbage - discarded anyway,
    // but keep clean for the planar store path)
    for (int l = tid; l < 2 * 264; l += 256) vT[30 * 264 + l] = __float2bfloat16(0.f);
    __syncthreads();

    const int rowbase = wl * 256 + w * 64;
    union U8 { unsigned int u[4]; bf16x8 v; };
    bf16x8 qf[4];
#pragma unroll
    for (int qi = 0; qi < 4; ++qi) {
        const unsigned int* p32 =
            (const unsigned int*)(qkv + (size_t)(rowbase + qi * 16 + fr) * 576 + h * 30);
        U8 t;
#pragma unroll
        for (int jj = 0; jj < 4; ++jj) t.u[jj] = p32[q * 4 + jj];
        qf[qi] = t.v;
    }

    const float SC = 0.18257418583505536f;
    float lsum[4] = {};
    floatx4 o_[4][2] = {};
    const __hip_bfloat16* rpbh = rpbN + (size_t)h * 65536;
    const float* maskw = mask + (size_t)wig * 65536;
    const int srcA = fr + ((q & 1) << 5);
    const int srcB = srcA + 16;

    for (int nc = 0; nc < 4; ++nc) {
        bf16x8 kf[4];
#pragma unroll
        for (int ki = 0; ki < 4; ++ki)
            kf[ki] = *(const bf16x8*)(kk + (nc * 64 + ki * 16 + fr) * 40 + q * 8);
        unsigned int dw[4][4][2];
#pragma unroll
        for (int qi = 0; qi < 4; ++qi) {
            floatx4 s_[4] = {};
#pragma unroll
            for (int ki = 0; ki < 4; ++ki)
                s_[ki] = __builtin_amdgcn_mfma_f32_16x16x32_bf16(kf[ki], qf[qi], s_[ki], 0, 0, 0);
            const size_t qoff = ((size_t)(w * 64 + qi * 16 + fr)) * 256 + nc * 64 + q * 4;
#pragma unroll
            for (int ki = 0; ki < 4; ++ki) {
                uint2 rb = *(const uint2*)(rpbh + qoff + ki * 16);
                float b0 = bflo(rb.x), b1 = bfhi(rb.x), b2 = bflo(rb.y), b3 = bfhi(rb.y);
                if (edge) {
                    float4 mv = *(const float4*)(maskw + qoff + ki * 16);
                    b0 += mv.x; b1 += mv.y; b2 += mv.z; b3 += mv.w;
                }
                float p0 = __expf(fmaf(s_[ki][0], SC, b0));
                float p1 = __expf(fmaf(s_[ki][1], SC, b1));
                float p2 = __expf(fmaf(s_[ki][2], SC, b2));
                float p3 = __expf(fmaf(s_[ki][3], SC, b3));
                lsum[qi] += (p0 + p1) + (p2 + p3);
                __hip_bfloat162 lo = {__float2bfloat16(p0), __float2bfloat16(p1)};
                __hip_bfloat162 hi = {__float2bfloat16(p2), __float2bfloat16(p3)};
                UB2 ul, uh; ul.h2 = lo; uh.h2 = hi;
                dw[ki][qi][0] = ul.u;
                dw[ki][qi][1] = uh.u;
            }
        }
#pragma unroll
        for (int kc = 0; kc < 2; ++kc) {
            bf16x8 pa[4];
#pragma unroll
            for (int mi = 0; mi < 4; ++mi) {
                unsigned g0 = __shfl((int)dw[2 * kc][mi][0], srcA, 64);
                unsigned g1 = __shfl((int)dw[2 * kc][mi][1], srcA, 64);
                unsigned g2 = __shfl((int)dw[2 * kc][mi][0], srcB, 64);
                unsigned g3 = __shfl((int)dw[2 * kc][mi][1], srcB, 64);
                unsigned h0 = __shfl((int)dw[2 * kc + 1][mi][0], srcA, 64);
                unsigned h1 = __shfl((int)dw[2 * kc + 1][mi][1], srcA, 64);
                unsigned h2 = __shfl((int)dw[2 * kc + 1][mi][0], srcB, 64);
                unsigned h3 = __shfl((int)dw[2 * kc + 1][mi][1], srcB, 64);
                U8 t;
                const bool lo = (q < 2);
                t.u[0] = lo ? g0 : h0;
                t.u[1] = lo ? g1 : h1;
                t.u[2] = lo ? g2 : h2;
                t.u[3] = lo ? g3 : h3;
                pa[mi] = t.v;
            }
            bf16x8 vb[2];
#pragma unroll
            for (int dj = 0; dj < 2; ++dj)
                vb[dj] = *(const bf16x8*)(vT + (dj * 16 + fr) * 264 + nc * 64 + kc * 32 + q * 8);
#pragma unroll
            for (int mi = 0; mi < 4; ++mi)
#pragma unroll
                for (int dj = 0; dj < 2; ++dj)
                    o_[mi][dj] =
                        __builtin_amdgcn_mfma_f32_16x16x32_bf16(pa[mi], vb[dj], o_[mi][dj], 0, 0, 0);
        }
    }
    // row sums: reduce across q-groups, redistribute via shfl
#pragma unroll
    for (int qi = 0; qi < 4; ++qi) {
        lsum[qi] += __shfl_xor(lsum[qi], 16, 64);
        lsum[qi] += __shfl_xor(lsum[qi], 32, 64);
    }
    __hip_bfloat16* plane = attn_out + (size_t)h * RCHUNK * 32;
#pragma unroll
    for (int mi = 0; mi < 4; ++mi) {
#pragma unroll
        for (int r = 0; r < 4; ++r) {
            float tot = __shfl(lsum[mi], q * 4 + r, 64);
            float inv = 1.f / tot;
            const int row_local = rowbase + mi * 16 + q * 4 + r;
            __hip_bfloat16* orow = plane + (size_t)row_local * 32;
#pragma unroll
            for (int dj = 0; dj < 2; ++dj) {
                int d = dj * 16 + fr;
                float val = (d < 30) ? o_[mi][dj][r] * inv : 0.f;
                orow[d] = __float2bfloat16(val);
            }
        }
    }
}

extern "C" void kernel_launch(void* const* d_in, const int* in_sizes, int n_in, void* d_out,
                              int out_size, void* d_ws, size_t ws_size, hipStream_t stream) {
    (void)in_sizes; (void)n_in; (void)out_size; (void)ws_size;
    const float* x = (const float*)d_in[0];
    const int* rpi = (const int*)d_in[3];
    const float* mask = (const float*)d_in[4];
    const float* n1g = (const float*)d_in[5];
    const float* n1b = (const float*)d_in[6];
    const float* qkvw = (const float*)d_in[7];
    const float* qkvb = (const float*)d_in[8];
    const float* rpbt = (const float*)d_in[9];
    const float* projw = (const float*)d_in[10];
    const float* projb = (const float*)d_in[11];
    const float* c1w = (const float*)d_in[12];
    const float* c1b = (const float*)d_in[13];
    const float* c2w = (const float*)d_in[14];
    const float* c2b = (const float*)d_in[15];
    const float* ca1w = (const float*)d_in[16];
    const float* ca1b = (const float*)d_in[17];
    const float* ca2w = (const float*)d_in[18];
    const float* ca2b = (const float*)d_in[19];
    const float* n2g = (const float*)d_in[20];
    const float* n2b = (const float*)d_in[21];
    const float* f1w = (const float*)d_in[22];
    const float* f1b = (const float*)d_in[23];
    const float* f2w = (const float*)d_in[24];
    const float* f2b = (const float*)d_in[25];

    float* ws = (float*)d_ws;
    float* out = (float*)d_out;  // y2 -> x2 -> final output (in place, disjoint phases)

    // workspace layout (floats; offsets 16B-aligned). ~77.8 MB total.
    float* xn_f     = ws;                    // 6,291,456 (65536x192 bf16)
    float* bufC     = xn_f + 6291456;        // 12,582,912 (y1b | qkvC+attnC | h1, all bf16)
    float* partials = bufC + 12582912;       // 46,080
    float* scalep   = partials + 46080;      // 192
    float* rpbN_f   = scalep + 192;          // 196,608 (6x65536 bf16)
    float* wb1_f    = rpbN_f + 196608;       // 55,296
    float* wb2_f    = wb1_f + 55296;         // 55,296
    float* qkvbt_f  = wb2_f + 55296;         // 61,440  (640x192 bf16)
    float* projbt_f = qkvbt_f + 61440;       // 18,432  (192x192 bf16)
    float* f1bt_f   = projbt_f + 18432;      // 73,728  (768x192 bf16)
    float* f2bt_f   = f1bt_f + 73728;        // 73,728  (192x768 bf16)

    __hip_bfloat16* xn    = (__hip_bfloat16*)xn_f;
    __hip_bfloat16* y1b   = (__hip_bfloat16*)bufC;                  // 65536x64
    __hip_bfloat16* qkvC  = (__hip_bfloat16*)bufC;                  // 32768x576
    __hip_bfloat16* attnC = (__hip_bfloat16*)(bufC + 9437184);      // 6x32768x32 planar
    __hip_bfloat16* h1    = (__hip_bfloat16*)bufC;                  // 32768x768
    __hip_bfloat16* rpbN   = (__hip_bfloat16*)rpbN_f;
    __hip_bfloat16* wb1    = (__hip_bfloat16*)wb1_f;
    __hip_bfloat16* wb2    = (__hip_bfloat16*)wb2_f;
    __hip_bfloat16* qkvbt  = (__hip_bfloat16*)qkvbt_f;
    __hip_bfloat16* projbt = (__hip_bfloat16*)projbt_f;
    __hip_bfloat16* f1bt   = (__hip_bfloat16*)f1bt_f;
    __hip_bfloat16* f2bt   = (__hip_bfloat16*)f2bt_f;

    // ---- fused prep (741,376 items) ----
    prep_all_k<<<(741376 + 255) / 256, 256, 0, stream>>>(rpi, rpbt, rpbN, c1w, wb1, c2w, wb2,
                                                         qkvw, qkvbt, projw, projbt,
                                                         f1w, f1bt, f2w, f2bt);

    // ---- LN1 -> bf16 ----
    ln_k<<<NTOK / 4, 256, 0, stream>>>(x, n1g, n1b, xn);

    // ---- CAB conv branch (MFMA): y2 lives in d_out ----
    mconv_k<8, 192, 60, 64, 1, 1><<<dim3(512, 1), 256, 0, stream>>>(xn, 192, wb1, c1b, y1b);
    mconv_k<16, 64, 180, 180, 0, 0><<<dim3(256, 3), 256, 0, stream>>>(y1b, 64, wb2, c2b, out);
    chansum_k<<<256, 192, 0, stream>>>(out, partials);
    ca_k<<<1, 256, 0, stream>>>(partials, ca1w, ca1b, ca2w, ca2b, scalep);

    // ---- attention branch, 2 chunks of 128 windows; proj epilogue fuses the merge ----
    for (int ck = 0; ck < 2; ++ck) {
        const int rowoff = ck * RCHUNK;
        mgemm_k<3, 128><<<dim3(5, RCHUNK / 128), 256, 0, stream>>>(
            (const unsigned short*)xn, (const unsigned short*)qkvbt, qkvb, nullptr, nullptr,
            qkvC, 192, 540, 576, rowoff);
        attn6_k<<<dim3(128, 6), 256, 0, stream>>>(qkvC, rpbN, mask, attnC, ck * 128);
        mgemm_k<5, 64><<<dim3(3, RCHUNK / 128), 256, 0, stream>>>(
            (const unsigned short*)attnC, (const unsigned short*)projbt, projb, x, scalep,
            out, 192, 180, RCHUNK, rowoff);
    }

    // ---- LN2 (x2 in d_out) -> bf16 xm ----
    ln_k<<<NTOK / 4, 256, 0, stream>>>(out, n2g, n2b, xn);

    // ---- MLP, 2 chunks; fc2 adds residual and overwrites d_out in place ----
    for (int ck = 0; ck < 2; ++ck) {
        const int rowoff = ck * RCHUNK;
        mgemm_k<1, 128><<<dim3(6, RCHUNK / 128), 256, 0, stream>>>(
            (const unsigned short*)(xn + (size_t)rowoff * KP1), (const unsigned short*)f1bt,
            f1b, nullptr, nullptr, h1, 192, 720, 768, 0);
        mgemm_k<2, 64><<<dim3(3, RCHUNK / 128), 256, 0, stream>>>(
            (const unsigned short*)h1, (const unsigned short*)f2bt, f2b,
            out + (size_t)rowoff * 180, nullptr, out + (size_t)rowoff * 180, 768, 180, 180, 0);
    }
}